// Round 3
// baseline (1692.398 us; speedup 1.0000x reference)
//
#include <hip/hip_runtime.h>
#include <math.h>

#define LSEQ 256
#define HID 256
#define H2 512
#define H3 768
#define H8 2048

typedef __attribute__((ext_vector_type(8))) short short8;
typedef __attribute__((ext_vector_type(4))) float floatx4;
typedef __attribute__((ext_vector_type(2))) float fx2;

__device__ __forceinline__ float sigmoidf_(float x) { return 1.f / (1.f + __expf(-x)); }
__device__ __forceinline__ unsigned short f2bf(float f) {
    unsigned int u = __float_as_uint(f);
    u = (u + 0x7FFFu + ((u >> 16) & 1u)) >> 16;
    return (unsigned short)u;
}
__device__ __forceinline__ float bf2f(unsigned short h) {
    return __uint_as_float(((unsigned int)h) << 16);
}
__device__ __forceinline__ float fsig(float x) {
    return __builtin_amdgcn_rcpf(1.f + __expf(-x));
}
__device__ __forceinline__ float ftanh(float x) {
    // 2*sigmoid(2x)-1; saturates correctly for large |x| (rcp(inf)=0 -> -1)
    return __builtin_fmaf(2.f, __builtin_amdgcn_rcpf(1.f + __expf(-2.f * x)), -1.f);
}

// ---------------- embed ----------------
__global__ void embed_kernel(const int* __restrict__ question,
                             const int* __restrict__ article,
                             const float* __restrict__ emb,
                             float* __restrict__ xemb) {
    int gid = blockIdx.x * 256 + threadIdx.x;   // 128*256*256
    int d = gid & 255;
    int rl = gid >> 8;
    int l = rl & 255;
    int stream = rl >> 8;
    int id;
    if (stream < 64) {
        int b = stream >> 3, o = (stream & 7) >> 1;
        id = question[(b * 4 + o) * 256 + l];
    } else {
        id = article[(stream - 64) * 256 + l];
    }
    xemb[(size_t)gid] = emb[(size_t)id * 256 + d];
}

// ---------------- MFMA bf16 GEMM ----------------
__global__ __launch_bounds__(256)
void gemm_mfma_bf16(const float* __restrict__ A, const float* __restrict__ B,
                    const float* __restrict__ bias, unsigned short* __restrict__ C,
                    int M, int N, int K) {
    __shared__ unsigned short At[128][40];
    __shared__ unsigned short Bt[128][40];
    int tid = threadIdx.x;
    int m0 = blockIdx.x * 128, n0 = blockIdx.y * 128;
    int l = tid & 63, w = tid >> 6;
    int wm = (w & 1) * 64, wn = (w >> 1) * 64;
    int lr = l & 15, koff = (l >> 4) * 8;
    int srow = tid >> 1, scol = (tid & 1) * 16;
    floatx4 acc[4][4];
#pragma unroll
    for (int i = 0; i < 4; i++)
#pragma unroll
        for (int j = 0; j < 4; j++) acc[i][j] = (floatx4){0.f, 0.f, 0.f, 0.f};
    for (int k0 = 0; k0 < K; k0 += 32) {
        const float* ap = A + (size_t)(m0 + srow) * K + k0 + scol;
        const float* bp = B + (size_t)(n0 + srow) * K + k0 + scol;
        float av[16], bv[16];
        *(float4*)&av[0]  = *(const float4*)(ap);
        *(float4*)&av[4]  = *(const float4*)(ap + 4);
        *(float4*)&av[8]  = *(const float4*)(ap + 8);
        *(float4*)&av[12] = *(const float4*)(ap + 12);
        *(float4*)&bv[0]  = *(const float4*)(bp);
        *(float4*)&bv[4]  = *(const float4*)(bp + 4);
        *(float4*)&bv[8]  = *(const float4*)(bp + 8);
        *(float4*)&bv[12] = *(const float4*)(bp + 12);
        unsigned int aw[8], bw[8];
#pragma unroll
        for (int i = 0; i < 8; i++) {
            aw[i] = (unsigned int)f2bf(av[2 * i]) | ((unsigned int)f2bf(av[2 * i + 1]) << 16);
            bw[i] = (unsigned int)f2bf(bv[2 * i]) | ((unsigned int)f2bf(bv[2 * i + 1]) << 16);
        }
        __syncthreads();
        *(uint4*)&At[srow][scol]     = *(uint4*)&aw[0];
        *(uint4*)&At[srow][scol + 8] = *(uint4*)&aw[4];
        *(uint4*)&Bt[srow][scol]     = *(uint4*)&bw[0];
        *(uint4*)&Bt[srow][scol + 8] = *(uint4*)&bw[4];
        __syncthreads();
        short8 af[4], bf[4];
#pragma unroll
        for (int i = 0; i < 4; i++) {
            af[i] = *(const short8*)&At[wm + i * 16 + lr][koff];
            bf[i] = *(const short8*)&Bt[wn + i * 16 + lr][koff];
        }
#pragma unroll
        for (int i = 0; i < 4; i++)
#pragma unroll
            for (int j = 0; j < 4; j++)
                acc[i][j] = __builtin_amdgcn_mfma_f32_16x16x32_bf16(af[i], bf[j], acc[i][j], 0, 0, 0);
    }
    int quad = l >> 4;
#pragma unroll
    for (int i = 0; i < 4; i++) {
#pragma unroll
        for (int j = 0; j < 4; j++) {
            int n = n0 + wn + j * 16 + lr;
            float bs = bias[n];
#pragma unroll
            for (int r = 0; r < 4; r++) {
                int m = m0 + wm + i * 16 + quad * 4 + r;
                C[(size_t)m * N + n] = f2bf(acc[i][j][r] + bs);
            }
        }
    }
}

// ---------------- whh pack to bf16 [d][768][256] row-major ----------------
__global__ void pack_whh_bf(const float* __restrict__ whh, unsigned short* __restrict__ wq) {
    int i = blockIdx.x * 256 + threadIdx.x;   // 2*768*256 = 393216
    wq[i] = f2bf(whh[i]);
}

// ---------------- GRU scan: 1 stream/block, whh in VGPRs, in-wave gates ----------------
// 512 threads = 8 waves. Wave w owns h-slice [32w, 32w+32): its 6 N-tiles are
// the r,z,n weight rows for that slice (tile nt -> gate nt>>1, sub nt&1,
// whh row = 256*(nt>>1) + 32w + 16*(nt&1) + lr).
// A-broadcast trick: all lanes read the same 16B of h -> every row of D equals
// the matvec -> acc[nt][0] is preact for col nt_base+(lane&15) in EVERY lane.
// So each lane computes 2 GRU cells fully in-register (x4 redundant across
// lane-quads, deterministic). h double-buffered in LDS -> ONE barrier/step,
// zero preact LDS traffic. gi prefetched 1 step ahead.
__global__ __launch_bounds__(512, 2)
void gru_scan_rreg(const unsigned short* __restrict__ gi_f,
                   const unsigned short* __restrict__ gi_b,
                   const unsigned short* __restrict__ whh_bf,
                   const float* __restrict__ bhh,
                   float* __restrict__ out) {
    int blk = blockIdx.x;
    int d = blk & 1, s = blk >> 1;
    const unsigned short* gi_blk = (d ? gi_b : gi_f) + (size_t)s * LSEQ * H3;
    const unsigned short* wb = whh_bf + (size_t)d * H3 * HID;

    __shared__ __align__(16) unsigned short h_pack[2][256];  // double-buffered h (bf16)

    int tid = threadIdx.x;
    int lane = tid & 63, wave = tid >> 6;
    int lr = lane & 15, kq = lane >> 4;

    // ---- preload weights into registers (B-fragment layout, gate-sliced rows) ----
    short8 bq[6][8];
#pragma unroll
    for (int nt = 0; nt < 6; nt++) {
        int row = (nt >> 1) * 256 + wave * 32 + (nt & 1) * 16 + lr;
        const unsigned short* wp = wb + (size_t)row * HID + kq * 8;
#pragma unroll
        for (int kt = 0; kt < 8; kt++)
            bq[nt][kt] = *(const short8*)(wp + kt * 32);
    }

    int hh0 = wave * 32 + lr, hh1 = hh0 + 16;
    float br0 = bhh[d * H3 + hh0],       br1 = bhh[d * H3 + hh1];
    float bz0 = bhh[d * H3 + 256 + hh0], bz1 = bhh[d * H3 + 256 + hh1];
    float bn0 = bhh[d * H3 + 512 + hh0], bn1 = bhh[d * H3 + 512 + hh1];

    int t0 = d ? (LSEQ - 1) : 0;
    int tstep = d ? -1 : 1;

    if (tid < 128) ((unsigned int*)h_pack[0])[tid] = 0;   // zero h buffer 0
    float hold0 = 0.f, hold1 = 0.f;

    // prologue: gi for first timestep
    unsigned short gr0, gz0, gn0, gr1, gz1, gn1;
    {
        const unsigned short* gp = gi_blk + (size_t)t0 * H3;
        gr0 = gp[hh0]; gz0 = gp[256 + hh0]; gn0 = gp[512 + hh0];
        gr1 = gp[hh1]; gz1 = gp[256 + hh1]; gn1 = gp[512 + hh1];
    }
    __syncthreads();

    int cur = 0, t = t0;
    for (int step = 0; step < LSEQ; ++step) {
        // prefetch next step's gi (hidden under MFMA phase)
        unsigned short nr0 = 0, nz0 = 0, nn0 = 0, nr1 = 0, nz1 = 0, nn1 = 0;
        if (step + 1 < LSEQ) {
            const unsigned short* gp = gi_blk + (size_t)(t + tstep) * H3;
            nr0 = gp[hh0]; nz0 = gp[256 + hh0]; nn0 = gp[512 + hh0];
            nr1 = gp[hh1]; nz1 = gp[256 + hh1]; nn1 = gp[512 + hh1];
        }
        // ---- MFMA phase: acc[nt][0] = preact for this wave's gate rows ----
        floatx4 acc[6];
#pragma unroll
        for (int nt = 0; nt < 6; nt++) acc[nt] = (floatx4){0.f, 0.f, 0.f, 0.f};
#pragma unroll
        for (int kt = 0; kt < 8; kt++) {
            short8 av = *(const short8*)&h_pack[cur][kt * 32 + kq * 8];  // broadcast
#pragma unroll
            for (int nt = 0; nt < 6; nt++)
                acc[nt] = __builtin_amdgcn_mfma_f32_16x16x32_bf16(av, bq[nt][kt], acc[nt], 0, 0, 0);
        }
        // ---- gate phase: 2 cells per lane, fully in-register ----
        float rg0 = fsig(bf2f(gr0) + acc[0][0] + br0);
        float rg1 = fsig(bf2f(gr1) + acc[1][0] + br1);
        float zg0 = fsig(bf2f(gz0) + acc[2][0] + bz0);
        float zg1 = fsig(bf2f(gz1) + acc[3][0] + bz1);
        float ng0 = ftanh(bf2f(gn0) + rg0 * (acc[4][0] + bn0));
        float ng1 = ftanh(bf2f(gn1) + rg1 * (acc[5][0] + bn1));
        float h0 = (1.f - zg0) * ng0 + zg0 * hold0;
        float h1 = (1.f - zg1) * ng1 + zg1 * hold1;
        hold0 = h0; hold1 = h1;
        int nxt = cur ^ 1;
        if (kq == 0) {
            h_pack[nxt][hh0] = f2bf(h0);
            h_pack[nxt][hh1] = f2bf(h1);
            float* op = out + ((size_t)s * LSEQ + t) * H2 + d * HID;
            op[hh0] = h0;
            op[hh1] = h1;
        }
        gr0 = nr0; gz0 = nz0; gn0 = nn0;
        gr1 = nr1; gz1 = nz1; gn1 = nn1;
        __syncthreads();
        cur = nxt; t += tstep;
    }
}

// ---------------- bidaf helpers (fp32, unchanged) ----------------
__global__ void cwqw_kernel(const float* __restrict__ c, const float* __restrict__ q,
                            const float* __restrict__ w,
                            float* __restrict__ cw, float* __restrict__ qw) {
    int row = blockIdx.x;
    int lane = threadIdx.x;
    const float* src; const float* wv; float* dst; int r;
    if (row < 16384) { src = c; wv = w; dst = cw; r = row; }
    else { src = q; wv = w + 512; dst = qw; r = row - 16384; }
    const float* p = src + (size_t)r * H2;
    float acc = 0.f;
    for (int j = lane; j < H2; j += 64) acc += p[j] * wv[j];
    for (int off = 32; off; off >>= 1) acc += __shfl_down(acc, off);
    if (lane == 0) dst[r] = acc;
}

__global__ __launch_bounds__(256)
void smat_kernel(const float* __restrict__ c, const float* __restrict__ q,
                 const float* __restrict__ w2, const float* __restrict__ bvec,
                 const float* __restrict__ cw, const float* __restrict__ qw,
                 float* __restrict__ smat) {
    int b = blockIdx.z;
    int m0 = blockIdx.x * 64, n0 = blockIdx.y * 64;
    const float* A = c + (size_t)b * LSEQ * H2;
    const float* B = q + (size_t)b * LSEQ * H2;
    __shared__ float As[16][64];
    __shared__ float Bs[16][64];
    int tid = threadIdx.x;
    int lr = tid >> 2, lc = (tid & 3) * 4;
    int tm = (tid >> 4) * 4, tn = (tid & 15) * 4;
    float acc[4][4];
#pragma unroll
    for (int i = 0; i < 4; i++)
#pragma unroll
        for (int j = 0; j < 4; j++) acc[i][j] = 0.f;
    for (int k0 = 0; k0 < H2; k0 += 16) {
        float4 av = *(const float4*)(A + (size_t)(m0 + lr) * H2 + k0 + lc);
        float4 wv = *(const float4*)(w2 + k0 + lc);
        As[lc + 0][lr] = av.x * wv.x; As[lc + 1][lr] = av.y * wv.y;
        As[lc + 2][lr] = av.z * wv.z; As[lc + 3][lr] = av.w * wv.w;
        float4 bv = *(const float4*)(B + (size_t)(n0 + lr) * H2 + k0 + lc);
        Bs[lc + 0][lr] = bv.x; Bs[lc + 1][lr] = bv.y; Bs[lc + 2][lr] = bv.z; Bs[lc + 3][lr] = bv.w;
        __syncthreads();
#pragma unroll
        for (int kk = 0; kk < 16; kk++) {
            float4 a0 = *(const float4*)&As[kk][tm];
            float4 b0 = *(const float4*)&Bs[kk][tn];
            float a[4] = {a0.x, a0.y, a0.z, a0.w};
            float bb4[4] = {b0.x, b0.y, b0.z, b0.w};
#pragma unroll
            for (int i = 0; i < 4; i++)
#pragma unroll
                for (int j = 0; j < 4; j++) acc[i][j] += a[i] * bb4[j];
        }
        __syncthreads();
    }
    float bsum = bvec[0] + bvec[1] + bvec[2];
#pragma unroll
    for (int i = 0; i < 4; i++) {
        int m = m0 + tm + i;
        float cwv = cw[b * LSEQ + m];
        float4 o;
        o.x = acc[i][0] + cwv + qw[b * LSEQ + n0 + tn + 0] + bsum;
        o.y = acc[i][1] + cwv + qw[b * LSEQ + n0 + tn + 1] + bsum;
        o.z = acc[i][2] + cwv + qw[b * LSEQ + n0 + tn + 2] + bsum;
        o.w = acc[i][3] + cwv + qw[b * LSEQ + n0 + tn + 3] + bsum;
        *(float4*)(smat + ((size_t)b * LSEQ + m) * LSEQ + n0 + tn) = o;
    }
}

__global__ void softmax_kernel(float* __restrict__ smat, float* __restrict__ rowmax) {
    int row = blockIdx.x;
    int lane = threadIdx.x;
    float* p = smat + (size_t)row * LSEQ;
    float v[4];
    float mx = -1e30f;
#pragma unroll
    for (int j = 0; j < 4; j++) { v[j] = p[lane + j * 64]; mx = fmaxf(mx, v[j]); }
    for (int off = 32; off; off >>= 1) mx = fmaxf(mx, __shfl_down(mx, off));
    mx = __shfl(mx, 0);
    float sum = 0.f;
#pragma unroll
    for (int j = 0; j < 4; j++) { v[j] = __expf(v[j] - mx); sum += v[j]; }
    for (int off = 32; off; off >>= 1) sum += __shfl_down(sum, off);
    sum = __shfl(sum, 0);
    float inv = 1.f / sum;
#pragma unroll
    for (int j = 0; j < 4; j++) p[lane + j * 64] = v[j] * inv;
    if (lane == 0) rowmax[row] = mx;
}

__global__ void bb_kernel(const float* __restrict__ rowmax, float* __restrict__ bb) {
    int b = blockIdx.x; int t = threadIdx.x;
    __shared__ float red[256];
    float v = rowmax[b * LSEQ + t];
    red[t] = v; __syncthreads();
    for (int s = 128; s; s >>= 1) { if (t < s) red[t] = fmaxf(red[t], red[t + s]); __syncthreads(); }
    float mx = red[0]; __syncthreads();
    float e = __expf(v - mx);
    red[t] = e; __syncthreads();
    for (int s = 128; s; s >>= 1) { if (t < s) red[t] += red[t + s]; __syncthreads(); }
    bb[b * LSEQ + t] = e / red[0];
}

__global__ void q2c_kernel(const float* __restrict__ bb, const float* __restrict__ c,
                           float* __restrict__ q2c) {
    int b = blockIdx.x; int t = threadIdx.x;
    float a0 = 0.f, a1 = 0.f;
    for (int i = 0; i < LSEQ; i++) {
        float w = bb[b * LSEQ + i];
        const float* row = c + ((size_t)b * LSEQ + i) * H2;
        a0 += w * row[t];
        a1 += w * row[t + 256];
    }
    q2c[b * H2 + t] = a0;
    q2c[b * H2 + t + 256] = a1;
}

__global__ __launch_bounds__(256)
void c2q_fixup(const float* __restrict__ amat, const float* __restrict__ q,
               const float* __restrict__ c, float* __restrict__ att, int add) {
    int b = blockIdx.z;
    int m0 = blockIdx.x * 64, n0 = blockIdx.y * 64;
    const float* A = amat + (size_t)b * LSEQ * LSEQ;
    const float* B = q + (size_t)b * LSEQ * H2;
    __shared__ float As[16][64];
    __shared__ float Bs[16][64];
    int tid = threadIdx.x;
    int lr = tid >> 2, lc = (tid & 3) * 4;
    int br = tid >> 4, bc = (tid & 15) * 4;
    int tm = (tid >> 4) * 4, tn = (tid & 15) * 4;
    float acc[4][4];
#pragma unroll
    for (int i = 0; i < 4; i++)
#pragma unroll
        for (int j = 0; j < 4; j++) acc[i][j] = 0.f;
    for (int k0 = 0; k0 < LSEQ; k0 += 16) {
        float4 av = *(const float4*)(A + (size_t)(m0 + lr) * LSEQ + k0 + lc);
        As[lc + 0][lr] = av.x; As[lc + 1][lr] = av.y; As[lc + 2][lr] = av.z; As[lc + 3][lr] = av.w;
        float4 bv = *(const float4*)(B + (size_t)(k0 + br) * H2 + n0 + bc);
        *(float4*)&Bs[br][bc] = bv;
        __syncthreads();
#pragma unroll
        for (int kk = 0; kk < 16; kk++) {
            float4 a0 = *(const float4*)&As[kk][tm];
            float4 b0 = *(const float4*)&Bs[kk][tn];
            float a[4] = {a0.x, a0.y, a0.z, a0.w};
            float bb4[4] = {b0.x, b0.y, b0.z, b0.w};
#pragma unroll
            for (int i = 0; i < 4; i++)
#pragma unroll
                for (int j = 0; j < 4; j++) acc[i][j] += a[i] * bb4[j];
        }
        __syncthreads();
    }
#pragma unroll
    for (int i = 0; i < 4; i++) {
        int row = b * LSEQ + m0 + tm + i;
        float4 cv = *(const float4*)(c + (size_t)row * H2 + n0 + tn);
        float4 v1, v2;
        v1.x = fmaxf(acc[i][0], 0.f); v1.y = fmaxf(acc[i][1], 0.f);
        v1.z = fmaxf(acc[i][2], 0.f); v1.w = fmaxf(acc[i][3], 0.f);
        v2.x = fmaxf(cv.x * acc[i][0], 0.f); v2.y = fmaxf(cv.y * acc[i][1], 0.f);
        v2.z = fmaxf(cv.z * acc[i][2], 0.f); v2.w = fmaxf(cv.w * acc[i][3], 0.f);
        float* p1 = att + (size_t)row * H8 + 512 + n0 + tn;
        float* p2 = att + (size_t)row * H8 + 1024 + n0 + tn;
        if (add) {
            float4 o1 = *(float4*)p1, o2 = *(float4*)p2;
            o1.x += v1.x; o1.y += v1.y; o1.z += v1.z; o1.w += v1.w;
            o2.x += v2.x; o2.y += v2.y; o2.z += v2.z; o2.w += v2.w;
            *(float4*)p1 = o1; *(float4*)p2 = o2;
        } else {
            *(float4*)p1 = v1; *(float4*)p2 = v2;
        }
    }
}

__global__ void fixup03(const float* __restrict__ c, const float* __restrict__ q2c,
                        float* __restrict__ att, int add) {
    int row = blockIdx.x;
    int t = threadIdx.x;
    int b = row >> 8;
    float* o = att + (size_t)row * H8;
#pragma unroll
    for (int rep = 0; rep < 2; rep++) {
        int d = t + rep * 256;
        float cv = c[(size_t)row * H2 + d];
        float qv = q2c[b * H2 + d];
        float v0 = fmaxf(cv, 0.f);
        float v3 = fmaxf(cv * qv, 0.f);
        if (add) { o[d] += v0; o[d + 1536] += v3; }
        else     { o[d]  = v0; o[d + 1536]  = v3; }
    }
}

// ---------------- final rank reduce ----------------
__global__ void reduce1_kernel(const float* __restrict__ s, const float* __restrict__ rw,
                               float* __restrict__ part) {
    int bo = blockIdx.x;
    int p = blockIdx.y;
    int t = threadIdx.x;
    const float* s0 = s + (size_t)(2 * bo) * 524288;
    const float* s1 = s0 + 524288;
    size_t base = (size_t)p * 65536;
    float acc = 0.f;
    for (int j = t; j < 65536; j += 256) {
        size_t m = base + j;
        acc += rw[m] * fmaxf(s0[m], s1[m]);
    }
    __shared__ float red[256];
    red[t] = acc; __syncthreads();
    for (int ss = 128; ss; ss >>= 1) { if (t < ss) red[t] += red[t + ss]; __syncthreads(); }
    if (t == 0) part[bo * 8 + p] = red[0];
}

__global__ void reduce2_kernel(const float* __restrict__ part, const float* __restrict__ rb,
                               float* __restrict__ out) {
    int t = threadIdx.x;
    float a = rb[0];
    for (int p = 0; p < 8; p++) a += part[t * 8 + p];
    out[t] = a;
}

extern "C" void kernel_launch(void* const* d_in, const int* in_sizes, int n_in,
                              void* d_out, int out_size, void* d_ws, size_t ws_size,
                              hipStream_t stream) {
    const int* question = (const int*)d_in[0];
    const int* article  = (const int*)d_in[1];
    const float* emb    = (const float*)d_in[2];
    const float* g1_wih = (const float*)d_in[3];
    const float* g1_whh = (const float*)d_in[4];
    const float* g1_bih = (const float*)d_in[5];
    const float* g1_bhh = (const float*)d_in[6];
    const float* g2_wih = (const float*)d_in[7];
    const float* g2_whh = (const float*)d_in[8];
    const float* g2_bih = (const float*)d_in[9];
    const float* g2_bhh = (const float*)d_in[10];
    const float* b1_w   = (const float*)d_in[11];
    const float* b1_b   = (const float*)d_in[12];
    const float* b2_w   = (const float*)d_in[13];
    const float* b2_b   = (const float*)d_in[14];
    const float* rank_w = (const float*)d_in[15];
    const float* rank_b = (const float*)d_in[16];
    float* ws = (float*)d_ws;
    float* out = (float*)d_out;

    // ---- workspace layout (fp32 slots) — peak 224 MiB (proven budget) ----
    float*          HBUF  = ws;
    float*          ATT   = ws + 16777216;
    float*          XEMB  = ws + 16777216;
    unsigned short* GI1B  = (unsigned short*)(ws + 25165824);  // 2 dirs x 32768 x 768 bf16
    unsigned short* WPK1  = (unsigned short*)(ws + 50331648);  // 393216 bf16 (768KB)
    float*          SMAT1 = ws + 50331648;
    float*          S1    = ws + 54525952;
    unsigned short* GI2B  = (unsigned short*)ws;               // 2 dirs x 16384 x 768 bf16
    unsigned short* WPK2  = (unsigned short*)(ws + 12582912);
    float*          AX2   = ws + 50331648;
    float*          SMAT2 = ws;
    float*          S2    = ws + 4194304;

    // 1. embed + pack whh1 (bf16 row-major [d][768][256])
    embed_kernel<<<32768, 256, 0, stream>>>(question, article, emb, XEMB);
    pack_whh_bf<<<1536, 256, 0, stream>>>(g1_whh, WPK1);

    // 2. GRU1 input gates via MFMA: per dir, M=32768 N=768 K=256
    for (int d = 0; d < 2; d++) {
        gemm_mfma_bf16<<<dim3(256, 6), 256, 0, stream>>>(
            XEMB, g1_wih + (size_t)d * 196608, g1_bih + d * 768,
            GI1B + (size_t)d * 32768 * 768, 32768, 768, 256);
    }
    // 3. GRU1 scan: 256 blocks (2 dirs x 128 streams) x 512 thr, reg-resident whh
    gru_scan_rreg<<<256, 512, 0, stream>>>(GI1B, GI1B + (size_t)32768 * 768, WPK1, g1_bhh, HBUF);

    float* QH = HBUF;
    float* AH = HBUF + (size_t)64 * 256 * 512;

    // 4. BiDAF1: c=QH, q=AH -> ATT (set)
    {
        float* CW = S1, *QW = S1 + 16384, *RM = S1 + 32768, *BBv = S1 + 49152, *Q2C = S1 + 65536;
        cwqw_kernel<<<32768, 64, 0, stream>>>(QH, AH, b1_w, CW, QW);
        smat_kernel<<<dim3(4, 4, 64), 256, 0, stream>>>(QH, AH, b1_w + 1024, b1_b, CW, QW, SMAT1);
        softmax_kernel<<<16384, 64, 0, stream>>>(SMAT1, RM);
        bb_kernel<<<64, 256, 0, stream>>>(RM, BBv);
        q2c_kernel<<<64, 256, 0, stream>>>(BBv, QH, Q2C);
        fixup03<<<16384, 256, 0, stream>>>(QH, Q2C, ATT, 0);
        c2q_fixup<<<dim3(4, 8, 64), 256, 0, stream>>>(SMAT1, AH, QH, ATT, 0);
    }

    // pack whh2 (HBUF dead, region free)
    pack_whh_bf<<<1536, 256, 0, stream>>>(g2_whh, WPK2);

    // 5. GRU2 input gates via MFMA: per dir, M=16384 N=768 K=2048
    for (int d = 0; d < 2; d++) {
        gemm_mfma_bf16<<<dim3(128, 6), 256, 0, stream>>>(
            ATT, g2_wih + (size_t)d * 1572864, g2_bih + d * 768,
            GI2B + (size_t)d * 16384 * 768, 16384, 768, 2048);
    }
    // 6. GRU2 scan: 128 blocks (2 dirs x 64 streams)
    gru_scan_rreg<<<128, 512, 0, stream>>>(GI2B, GI2B + (size_t)16384 * 768, WPK2, g2_bhh, AX2);

    // 7. BiDAF2: c=q=AX2 -> ATT (accumulate)
    {
        float* CW = S2, *QW = S2 + 16384, *RM = S2 + 32768, *BBv = S2 + 49152, *Q2C = S2 + 65536;
        cwqw_kernel<<<32768, 64, 0, stream>>>(AX2, AX2, b2_w, CW, QW);
        smat_kernel<<<dim3(4, 4, 64), 256, 0, stream>>>(AX2, AX2, b2_w + 1024, b2_b, CW, QW, SMAT2);
        softmax_kernel<<<16384, 64, 0, stream>>>(SMAT2, RM);
        bb_kernel<<<64, 256, 0, stream>>>(RM, BBv);
        q2c_kernel<<<64, 256, 0, stream>>>(BBv, AX2, Q2C);
        fixup03<<<16384, 256, 0, stream>>>(AX2, Q2C, ATT, 1);
        c2q_fixup<<<dim3(4, 8, 64), 256, 0, stream>>>(SMAT2, AX2, AX2, ATT, 1);
    }

    // 8. rank reduce
    float* PART = S2 + 98304;
    reduce1_kernel<<<dim3(32, 8), 256, 0, stream>>>(ATT, rank_w, PART);
    reduce2_kernel<<<1, 32, 0, stream>>>(PART, rank_b, out);
}

// Round 4
// 1478.215 us; speedup vs baseline: 1.1449x; 1.1449x over previous
//
#include <hip/hip_runtime.h>
#include <math.h>

#define LSEQ 256
#define HID 256
#define H2 512
#define H3 768
#define H8 2048

typedef __attribute__((ext_vector_type(8))) short short8;
typedef __attribute__((ext_vector_type(4))) float floatx4;

__device__ __forceinline__ unsigned short f2bf(float f) {
    unsigned int u = __float_as_uint(f);
    u = (u + 0x7FFFu + ((u >> 16) & 1u)) >> 16;
    return (unsigned short)u;
}
__device__ __forceinline__ float bf2f(unsigned short h) {
    return __uint_as_float(((unsigned int)h) << 16);
}
__device__ __forceinline__ float fsig(float x) {
    return __builtin_amdgcn_rcpf(1.f + __expf(-x));
}
__device__ __forceinline__ float ftanh(float x) {
    return __builtin_fmaf(2.f, __builtin_amdgcn_rcpf(1.f + __expf(-2.f * x)), -1.f);
}

// ---------------- embed (bf16 out) ----------------
__global__ void embed_kernel(const int* __restrict__ question,
                             const int* __restrict__ article,
                             const float* __restrict__ emb,
                             unsigned short* __restrict__ xemb) {
    int gid = blockIdx.x * 256 + threadIdx.x;   // 128*256*256
    int d = gid & 255;
    int rl = gid >> 8;
    int l = rl & 255;
    int stream = rl >> 8;
    int id;
    if (stream < 64) {
        int b = stream >> 3, o = (stream & 7) >> 1;
        id = question[(b * 4 + o) * 256 + l];
    } else {
        id = article[(stream - 64) * 256 + l];
    }
    xemb[(size_t)gid] = f2bf(emb[(size_t)id * 256 + d]);
}

// ---------------- generic fp32 -> bf16 pack ----------------
__global__ void pack_bf(const float* __restrict__ src, unsigned short* __restrict__ dst, int n) {
    int i = blockIdx.x * 256 + threadIdx.x;
    if (i < n) dst[i] = f2bf(src[i]);
}

// ---------------- MFMA GEMM: A bf16, B bf16 (both pre-packed) ----------------
__global__ __launch_bounds__(256)
void gemm_a16b16(const unsigned short* __restrict__ A, const unsigned short* __restrict__ B,
                 const float* __restrict__ bias, unsigned short* __restrict__ C,
                 int M, int N, int K) {
    __shared__ unsigned short At[128][40];
    __shared__ unsigned short Bt[128][40];
    int tid = threadIdx.x;
    int m0 = blockIdx.x * 128, n0 = blockIdx.y * 128;
    int l = tid & 63, w = tid >> 6;
    int wm = (w & 1) * 64, wn = (w >> 1) * 64;
    int lr = l & 15, koff = (l >> 4) * 8;
    int srow = tid >> 1, scol = (tid & 1) * 16;
    floatx4 acc[4][4];
#pragma unroll
    for (int i = 0; i < 4; i++)
#pragma unroll
        for (int j = 0; j < 4; j++) acc[i][j] = (floatx4){0.f, 0.f, 0.f, 0.f};
    for (int k0 = 0; k0 < K; k0 += 32) {
        const unsigned short* ap = A + (size_t)(m0 + srow) * K + k0 + scol;
        const unsigned short* bp = B + (size_t)(n0 + srow) * K + k0 + scol;
        uint4 a0 = *(const uint4*)(ap);
        uint4 a1 = *(const uint4*)(ap + 8);
        uint4 b0 = *(const uint4*)(bp);
        uint4 b1 = *(const uint4*)(bp + 8);
        __syncthreads();
        *(uint4*)&At[srow][scol]     = a0;
        *(uint4*)&At[srow][scol + 8] = a1;
        *(uint4*)&Bt[srow][scol]     = b0;
        *(uint4*)&Bt[srow][scol + 8] = b1;
        __syncthreads();
        short8 af[4], bf[4];
#pragma unroll
        for (int i = 0; i < 4; i++) {
            af[i] = *(const short8*)&At[wm + i * 16 + lr][koff];
            bf[i] = *(const short8*)&Bt[wn + i * 16 + lr][koff];
        }
#pragma unroll
        for (int i = 0; i < 4; i++)
#pragma unroll
            for (int j = 0; j < 4; j++)
                acc[i][j] = __builtin_amdgcn_mfma_f32_16x16x32_bf16(af[i], bf[j], acc[i][j], 0, 0, 0);
    }
    int quad = l >> 4;
#pragma unroll
    for (int i = 0; i < 4; i++) {
#pragma unroll
        for (int j = 0; j < 4; j++) {
            int n = n0 + wn + j * 16 + lr;
            float bs = bias[n];
#pragma unroll
            for (int r = 0; r < 4; r++) {
                int m = m0 + wm + i * 16 + quad * 4 + r;
                C[(size_t)m * N + n] = f2bf(acc[i][j][r] + bs);
            }
        }
    }
}

// ---------------- MFMA GEMM: A fp32 (convert in-kernel), B bf16 pre-packed ----------------
__global__ __launch_bounds__(256)
void gemm_a32b16(const float* __restrict__ A, const unsigned short* __restrict__ B,
                 const float* __restrict__ bias, unsigned short* __restrict__ C,
                 int M, int N, int K) {
    __shared__ unsigned short At[128][40];
    __shared__ unsigned short Bt[128][40];
    int tid = threadIdx.x;
    int m0 = blockIdx.x * 128, n0 = blockIdx.y * 128;
    int l = tid & 63, w = tid >> 6;
    int wm = (w & 1) * 64, wn = (w >> 1) * 64;
    int lr = l & 15, koff = (l >> 4) * 8;
    int srow = tid >> 1, scol = (tid & 1) * 16;
    floatx4 acc[4][4];
#pragma unroll
    for (int i = 0; i < 4; i++)
#pragma unroll
        for (int j = 0; j < 4; j++) acc[i][j] = (floatx4){0.f, 0.f, 0.f, 0.f};
    for (int k0 = 0; k0 < K; k0 += 32) {
        const float* ap = A + (size_t)(m0 + srow) * K + k0 + scol;
        const unsigned short* bp = B + (size_t)(n0 + srow) * K + k0 + scol;
        float av[16];
        *(float4*)&av[0]  = *(const float4*)(ap);
        *(float4*)&av[4]  = *(const float4*)(ap + 4);
        *(float4*)&av[8]  = *(const float4*)(ap + 8);
        *(float4*)&av[12] = *(const float4*)(ap + 12);
        uint4 b0 = *(const uint4*)(bp);
        uint4 b1 = *(const uint4*)(bp + 8);
        unsigned int aw[8];
#pragma unroll
        for (int i = 0; i < 8; i++)
            aw[i] = (unsigned int)f2bf(av[2 * i]) | ((unsigned int)f2bf(av[2 * i + 1]) << 16);
        __syncthreads();
        *(uint4*)&At[srow][scol]     = *(uint4*)&aw[0];
        *(uint4*)&At[srow][scol + 8] = *(uint4*)&aw[4];
        *(uint4*)&Bt[srow][scol]     = b0;
        *(uint4*)&Bt[srow][scol + 8] = b1;
        __syncthreads();
        short8 af[4], bf[4];
#pragma unroll
        for (int i = 0; i < 4; i++) {
            af[i] = *(const short8*)&At[wm + i * 16 + lr][koff];
            bf[i] = *(const short8*)&Bt[wn + i * 16 + lr][koff];
        }
#pragma unroll
        for (int i = 0; i < 4; i++)
#pragma unroll
            for (int j = 0; j < 4; j++)
                acc[i][j] = __builtin_amdgcn_mfma_f32_16x16x32_bf16(af[i], bf[j], acc[i][j], 0, 0, 0);
    }
    int quad = l >> 4;
#pragma unroll
    for (int i = 0; i < 4; i++) {
#pragma unroll
        for (int j = 0; j < 4; j++) {
            int n = n0 + wn + j * 16 + lr;
            float bs = bias[n];
#pragma unroll
            for (int r = 0; r < 4; r++) {
                int m = m0 + wm + i * 16 + quad * 4 + r;
                C[(size_t)m * N + n] = f2bf(acc[i][j][r] + bs);
            }
        }
    }
}

// ---------------- GRU scan: 1 stream/block, whh in VGPRs, in-wave gates ----------------
__global__ __launch_bounds__(512, 2)
void gru_scan_rreg(const unsigned short* __restrict__ gi_f,
                   const unsigned short* __restrict__ gi_b,
                   const unsigned short* __restrict__ whh_bf,
                   const float* __restrict__ bhh,
                   float* __restrict__ out) {
    int blk = blockIdx.x;
    int d = blk & 1, s = blk >> 1;
    const unsigned short* gi_blk = (d ? gi_b : gi_f) + (size_t)s * LSEQ * H3;
    const unsigned short* wb = whh_bf + (size_t)d * H3 * HID;

    __shared__ __align__(16) unsigned short h_pack[2][256];  // double-buffered h (bf16)

    int tid = threadIdx.x;
    int lane = tid & 63, wave = tid >> 6;
    int lr = lane & 15, kq = lane >> 4;

    short8 bq[6][8];
#pragma unroll
    for (int nt = 0; nt < 6; nt++) {
        int row = (nt >> 1) * 256 + wave * 32 + (nt & 1) * 16 + lr;
        const unsigned short* wp = wb + (size_t)row * HID + kq * 8;
#pragma unroll
        for (int kt = 0; kt < 8; kt++)
            bq[nt][kt] = *(const short8*)(wp + kt * 32);
    }

    int hh0 = wave * 32 + lr, hh1 = hh0 + 16;
    float br0 = bhh[d * H3 + hh0],       br1 = bhh[d * H3 + hh1];
    float bz0 = bhh[d * H3 + 256 + hh0], bz1 = bhh[d * H3 + 256 + hh1];
    float bn0 = bhh[d * H3 + 512 + hh0], bn1 = bhh[d * H3 + 512 + hh1];

    int t0 = d ? (LSEQ - 1) : 0;
    int tstep = d ? -1 : 1;

    if (tid < 128) ((unsigned int*)h_pack[0])[tid] = 0;
    float hold0 = 0.f, hold1 = 0.f;

    unsigned short gr0, gz0, gn0, gr1, gz1, gn1;
    {
        const unsigned short* gp = gi_blk + (size_t)t0 * H3;
        gr0 = gp[hh0]; gz0 = gp[256 + hh0]; gn0 = gp[512 + hh0];
        gr1 = gp[hh1]; gz1 = gp[256 + hh1]; gn1 = gp[512 + hh1];
    }
    __syncthreads();

    int cur = 0, t = t0;
    for (int step = 0; step < LSEQ; ++step) {
        unsigned short nr0 = 0, nz0 = 0, nn0 = 0, nr1 = 0, nz1 = 0, nn1 = 0;
        if (step + 1 < LSEQ) {
            const unsigned short* gp = gi_blk + (size_t)(t + tstep) * H3;
            nr0 = gp[hh0]; nz0 = gp[256 + hh0]; nn0 = gp[512 + hh0];
            nr1 = gp[hh1]; nz1 = gp[256 + hh1]; nn1 = gp[512 + hh1];
        }
        floatx4 acc[6];
#pragma unroll
        for (int nt = 0; nt < 6; nt++) acc[nt] = (floatx4){0.f, 0.f, 0.f, 0.f};
#pragma unroll
        for (int kt = 0; kt < 8; kt++) {
            short8 av = *(const short8*)&h_pack[cur][kt * 32 + kq * 8];  // broadcast
#pragma unroll
            for (int nt = 0; nt < 6; nt++)
                acc[nt] = __builtin_amdgcn_mfma_f32_16x16x32_bf16(av, bq[nt][kt], acc[nt], 0, 0, 0);
        }
        float rg0 = fsig(bf2f(gr0) + acc[0][0] + br0);
        float rg1 = fsig(bf2f(gr1) + acc[1][0] + br1);
        float zg0 = fsig(bf2f(gz0) + acc[2][0] + bz0);
        float zg1 = fsig(bf2f(gz1) + acc[3][0] + bz1);
        float ng0 = ftanh(bf2f(gn0) + rg0 * (acc[4][0] + bn0));
        float ng1 = ftanh(bf2f(gn1) + rg1 * (acc[5][0] + bn1));
        float h0 = (1.f - zg0) * ng0 + zg0 * hold0;
        float h1 = (1.f - zg1) * ng1 + zg1 * hold1;
        hold0 = h0; hold1 = h1;
        int nxt = cur ^ 1;
        if (kq == 0) {
            h_pack[nxt][hh0] = f2bf(h0);
            h_pack[nxt][hh1] = f2bf(h1);
            float* op = out + ((size_t)s * LSEQ + t) * H2 + d * HID;
            op[hh0] = h0;
            op[hh1] = h1;
        }
        gr0 = nr0; gz0 = nz0; gn0 = nn0;
        gr1 = nr1; gz1 = nz1; gn1 = nn1;
        __syncthreads();
        cur = nxt; t += tstep;
    }
}

// ---------------- bidaf helpers ----------------
__global__ void cwqw_kernel(const float* __restrict__ c, const float* __restrict__ q,
                            const float* __restrict__ w,
                            float* __restrict__ cw, float* __restrict__ qw) {
    int row = blockIdx.x;
    int lane = threadIdx.x;
    const float* src; const float* wv; float* dst; int r;
    if (row < 16384) { src = c; wv = w; dst = cw; r = row; }
    else { src = q; wv = w + 512; dst = qw; r = row - 16384; }
    const float* p = src + (size_t)r * H2;
    float acc = 0.f;
    for (int j = lane; j < H2; j += 64) acc += p[j] * wv[j];
    for (int off = 32; off; off >>= 1) acc += __shfl_down(acc, off);
    if (lane == 0) dst[r] = acc;
}

__global__ __launch_bounds__(256)
void smat_kernel(const float* __restrict__ c, const float* __restrict__ q,
                 const float* __restrict__ w2, const float* __restrict__ bvec,
                 const float* __restrict__ cw, const float* __restrict__ qw,
                 float* __restrict__ smat) {
    int b = blockIdx.z;
    int m0 = blockIdx.x * 64, n0 = blockIdx.y * 64;
    const float* A = c + (size_t)b * LSEQ * H2;
    const float* B = q + (size_t)b * LSEQ * H2;
    __shared__ float As[16][64];
    __shared__ float Bs[16][64];
    int tid = threadIdx.x;
    int lr = tid >> 2, lc = (tid & 3) * 4;
    int tm = (tid >> 4) * 4, tn = (tid & 15) * 4;
    float acc[4][4];
#pragma unroll
    for (int i = 0; i < 4; i++)
#pragma unroll
        for (int j = 0; j < 4; j++) acc[i][j] = 0.f;
    for (int k0 = 0; k0 < H2; k0 += 16) {
        float4 av = *(const float4*)(A + (size_t)(m0 + lr) * H2 + k0 + lc);
        float4 wv = *(const float4*)(w2 + k0 + lc);
        As[lc + 0][lr] = av.x * wv.x; As[lc + 1][lr] = av.y * wv.y;
        As[lc + 2][lr] = av.z * wv.z; As[lc + 3][lr] = av.w * wv.w;
        float4 bv = *(const float4*)(B + (size_t)(n0 + lr) * H2 + k0 + lc);
        Bs[lc + 0][lr] = bv.x; Bs[lc + 1][lr] = bv.y; Bs[lc + 2][lr] = bv.z; Bs[lc + 3][lr] = bv.w;
        __syncthreads();
#pragma unroll
        for (int kk = 0; kk < 16; kk++) {
            float4 a0 = *(const float4*)&As[kk][tm];
            float4 b0 = *(const float4*)&Bs[kk][tn];
            float a[4] = {a0.x, a0.y, a0.z, a0.w};
            float bb4[4] = {b0.x, b0.y, b0.z, b0.w};
#pragma unroll
            for (int i = 0; i < 4; i++)
#pragma unroll
                for (int j = 0; j < 4; j++) acc[i][j] += a[i] * bb4[j];
        }
        __syncthreads();
    }
    float bsum = bvec[0] + bvec[1] + bvec[2];
#pragma unroll
    for (int i = 0; i < 4; i++) {
        int m = m0 + tm + i;
        float cwv = cw[b * LSEQ + m];
        float4 o;
        o.x = acc[i][0] + cwv + qw[b * LSEQ + n0 + tn + 0] + bsum;
        o.y = acc[i][1] + cwv + qw[b * LSEQ + n0 + tn + 1] + bsum;
        o.z = acc[i][2] + cwv + qw[b * LSEQ + n0 + tn + 2] + bsum;
        o.w = acc[i][3] + cwv + qw[b * LSEQ + n0 + tn + 3] + bsum;
        *(float4*)(smat + ((size_t)b * LSEQ + m) * LSEQ + n0 + tn) = o;
    }
}

__global__ void softmax_kernel(float* __restrict__ smat, float* __restrict__ rowmax) {
    int row = blockIdx.x;
    int lane = threadIdx.x;
    float* p = smat + (size_t)row * LSEQ;
    float v[4];
    float mx = -1e30f;
#pragma unroll
    for (int j = 0; j < 4; j++) { v[j] = p[lane + j * 64]; mx = fmaxf(mx, v[j]); }
    for (int off = 32; off; off >>= 1) mx = fmaxf(mx, __shfl_down(mx, off));
    mx = __shfl(mx, 0);
    float sum = 0.f;
#pragma unroll
    for (int j = 0; j < 4; j++) { v[j] = __expf(v[j] - mx); sum += v[j]; }
    for (int off = 32; off; off >>= 1) sum += __shfl_down(sum, off);
    sum = __shfl(sum, 0);
    float inv = 1.f / sum;
#pragma unroll
    for (int j = 0; j < 4; j++) p[lane + j * 64] = v[j] * inv;
    if (lane == 0) rowmax[row] = mx;
}

__global__ void bb_kernel(const float* __restrict__ rowmax, float* __restrict__ bb) {
    int b = blockIdx.x; int t = threadIdx.x;
    __shared__ float red[256];
    float v = rowmax[b * LSEQ + t];
    red[t] = v; __syncthreads();
    for (int s = 128; s; s >>= 1) { if (t < s) red[t] = fmaxf(red[t], red[t + s]); __syncthreads(); }
    float mx = red[0]; __syncthreads();
    float e = __expf(v - mx);
    red[t] = e; __syncthreads();
    for (int s = 128; s; s >>= 1) { if (t < s) red[t] += red[t + s]; __syncthreads(); }
    bb[b * LSEQ + t] = e / red[0];
}

// q2c: grid (64,4) x 128 thr; 4 independent accumulators break the add chain
__global__ void q2c_kernel(const float* __restrict__ bb, const float* __restrict__ c,
                           float* __restrict__ q2c) {
    int b = blockIdx.x;
    int d = blockIdx.y * 128 + threadIdx.x;
    const float* cb = c + (size_t)b * LSEQ * H2 + d;
    const float* bbp = bb + b * LSEQ;
    float a0 = 0.f, a1 = 0.f, a2 = 0.f, a3 = 0.f;
    for (int i = 0; i < LSEQ; i += 4) {
        a0 += bbp[i]     * cb[(size_t)i * H2];
        a1 += bbp[i + 1] * cb[(size_t)(i + 1) * H2];
        a2 += bbp[i + 2] * cb[(size_t)(i + 2) * H2];
        a3 += bbp[i + 3] * cb[(size_t)(i + 3) * H2];
    }
    q2c[b * H2 + d] = (a0 + a1) + (a2 + a3);
}

__global__ __launch_bounds__(256)
void c2q_fixup(const float* __restrict__ amat, const float* __restrict__ q,
               const float* __restrict__ c, float* __restrict__ att, int add) {
    int b = blockIdx.z;
    int m0 = blockIdx.x * 64, n0 = blockIdx.y * 64;
    const float* A = amat + (size_t)b * LSEQ * LSEQ;
    const float* B = q + (size_t)b * LSEQ * H2;
    __shared__ float As[16][64];
    __shared__ float Bs[16][64];
    int tid = threadIdx.x;
    int lr = tid >> 2, lc = (tid & 3) * 4;
    int br = tid >> 4, bc = (tid & 15) * 4;
    int tm = (tid >> 4) * 4, tn = (tid & 15) * 4;
    float acc[4][4];
#pragma unroll
    for (int i = 0; i < 4; i++)
#pragma unroll
        for (int j = 0; j < 4; j++) acc[i][j] = 0.f;
    for (int k0 = 0; k0 < LSEQ; k0 += 16) {
        float4 av = *(const float4*)(A + (size_t)(m0 + lr) * LSEQ + k0 + lc);
        As[lc + 0][lr] = av.x; As[lc + 1][lr] = av.y; As[lc + 2][lr] = av.z; As[lc + 3][lr] = av.w;
        float4 bv = *(const float4*)(B + (size_t)(k0 + br) * H2 + n0 + bc);
        *(float4*)&Bs[br][bc] = bv;
        __syncthreads();
#pragma unroll
        for (int kk = 0; kk < 16; kk++) {
            float4 a0 = *(const float4*)&As[kk][tm];
            float4 b0 = *(const float4*)&Bs[kk][tn];
            float a[4] = {a0.x, a0.y, a0.z, a0.w};
            float bb4[4] = {b0.x, b0.y, b0.z, b0.w};
#pragma unroll
            for (int i = 0; i < 4; i++)
#pragma unroll
                for (int j = 0; j < 4; j++) acc[i][j] += a[i] * bb4[j];
        }
        __syncthreads();
    }
#pragma unroll
    for (int i = 0; i < 4; i++) {
        int row = b * LSEQ + m0 + tm + i;
        float4 cv = *(const float4*)(c + (size_t)row * H2 + n0 + tn);
        float4 v1, v2;
        v1.x = fmaxf(acc[i][0], 0.f); v1.y = fmaxf(acc[i][1], 0.f);
        v1.z = fmaxf(acc[i][2], 0.f); v1.w = fmaxf(acc[i][3], 0.f);
        v2.x = fmaxf(cv.x * acc[i][0], 0.f); v2.y = fmaxf(cv.y * acc[i][1], 0.f);
        v2.z = fmaxf(cv.z * acc[i][2], 0.f); v2.w = fmaxf(cv.w * acc[i][3], 0.f);
        float* p1 = att + (size_t)row * H8 + 512 + n0 + tn;
        float* p2 = att + (size_t)row * H8 + 1024 + n0 + tn;
        if (add) {
            float4 o1 = *(float4*)p1, o2 = *(float4*)p2;
            o1.x += v1.x; o1.y += v1.y; o1.z += v1.z; o1.w += v1.w;
            o2.x += v2.x; o2.y += v2.y; o2.z += v2.z; o2.w += v2.w;
            *(float4*)p1 = o1; *(float4*)p2 = o2;
        } else {
            *(float4*)p1 = v1; *(float4*)p2 = v2;
        }
    }
}

__global__ void fixup03(const float* __restrict__ c, const float* __restrict__ q2c,
                        float* __restrict__ att, int add) {
    int row = blockIdx.x;
    int t = threadIdx.x;
    int b = row >> 8;
    float* o = att + (size_t)row * H8;
#pragma unroll
    for (int rep = 0; rep < 2; rep++) {
        int d = t + rep * 256;
        float cv = c[(size_t)row * H2 + d];
        float qv = q2c[b * H2 + d];
        float v0 = fmaxf(cv, 0.f);
        float v3 = fmaxf(cv * qv, 0.f);
        if (add) { o[d] += v0; o[d + 1536] += v3; }
        else     { o[d]  = v0; o[d + 1536]  = v3; }
    }
}

// ---------------- final rank reduce ----------------
__global__ void reduce1_kernel(const float* __restrict__ s, const float* __restrict__ rw,
                               float* __restrict__ part) {
    int bo = blockIdx.x;
    int p = blockIdx.y;
    int t = threadIdx.x;
    const float* s0 = s + (size_t)(2 * bo) * 524288;
    const float* s1 = s0 + 524288;
    size_t base = (size_t)p * 65536;
    float acc = 0.f;
    for (int j = t; j < 65536; j += 256) {
        size_t m = base + j;
        acc += rw[m] * fmaxf(s0[m], s1[m]);
    }
    __shared__ float red[256];
    red[t] = acc; __syncthreads();
    for (int ss = 128; ss; ss >>= 1) { if (t < ss) red[t] += red[t + ss]; __syncthreads(); }
    if (t == 0) part[bo * 8 + p] = red[0];
}

__global__ void reduce2_kernel(const float* __restrict__ part, const float* __restrict__ rb,
                               float* __restrict__ out) {
    int t = threadIdx.x;
    float a = rb[0];
    for (int p = 0; p < 8; p++) a += part[t * 8 + p];
    out[t] = a;
}

extern "C" void kernel_launch(void* const* d_in, const int* in_sizes, int n_in,
                              void* d_out, int out_size, void* d_ws, size_t ws_size,
                              hipStream_t stream) {
    const int* question = (const int*)d_in[0];
    const int* article  = (const int*)d_in[1];
    const float* emb    = (const float*)d_in[2];
    const float* g1_wih = (const float*)d_in[3];
    const float* g1_whh = (const float*)d_in[4];
    const float* g1_bih = (const float*)d_in[5];
    const float* g1_bhh = (const float*)d_in[6];
    const float* g2_wih = (const float*)d_in[7];
    const float* g2_whh = (const float*)d_in[8];
    const float* g2_bih = (const float*)d_in[9];
    const float* g2_bhh = (const float*)d_in[10];
    const float* b1_w   = (const float*)d_in[11];
    const float* b1_b   = (const float*)d_in[12];
    const float* b2_w   = (const float*)d_in[13];
    const float* b2_b   = (const float*)d_in[14];
    const float* rank_w = (const float*)d_in[15];
    const float* rank_b = (const float*)d_in[16];
    float* ws = (float*)d_ws;
    float* out = (float*)d_out;

    // ---- workspace layout (float offsets; phase-liveness verified) ----
    // SCR  [0, 2293760): packed weights + scratch (persistent)
    // slot [2293760, 14876672): XEMBB (P1-2) / SMAT (P4,P7) / GI2B (P5-6)
    // HBUF [6488064, 23265280): scan1 out (P3-4)
    // AX2  [14876672, 23265280): scan2 out (P6-7)
    // ATT  [25165824, 58720256): P4 -> end; GI1B (P2-3) aliases its head
    unsigned short* WPK1  = (unsigned short*)(ws);
    unsigned short* WIH1B = (unsigned short*)(ws + 196608);
    unsigned short* WPK2  = (unsigned short*)(ws + 393216);
    unsigned short* WIH2B = (unsigned short*)(ws + 589824);
    float* CW   = ws + 2162688;
    float* QW   = ws + 2179072;
    float* RM   = ws + 2195456;
    float* BBv  = ws + 2211840;
    float* Q2C  = ws + 2228224;
    float* PART = ws + 2260992;
    unsigned short* XEMBB = (unsigned short*)(ws + 2293760);
    float*          SMAT  = ws + 2293760;
    unsigned short* GI2B  = (unsigned short*)(ws + 2293760);
    float*          HBUF  = ws + 6488064;
    float*          AX2   = ws + 14876672;
    float*          ATT   = ws + 25165824;
    unsigned short* GI1B  = (unsigned short*)(ws + 25165824);

    // 1. embed (bf16) + pack all weights to bf16
    embed_kernel<<<32768, 256, 0, stream>>>(question, article, emb, XEMBB);
    pack_bf<<<1536, 256, 0, stream>>>(g1_whh, WPK1, 393216);
    pack_bf<<<1536, 256, 0, stream>>>(g1_wih, WIH1B, 393216);
    pack_bf<<<1536, 256, 0, stream>>>(g2_whh, WPK2, 393216);
    pack_bf<<<12288, 256, 0, stream>>>(g2_wih, WIH2B, 3145728);

    // 2. GRU1 input gates: per dir, M=32768 N=768 K=256, all-bf16
    for (int d = 0; d < 2; d++) {
        gemm_a16b16<<<dim3(256, 6), 256, 0, stream>>>(
            XEMBB, WIH1B + (size_t)d * 196608, g1_bih + d * 768,
            GI1B + (size_t)d * 25165824, 32768, 768, 256);
    }
    // 3. GRU1 scan
    gru_scan_rreg<<<256, 512, 0, stream>>>(GI1B, GI1B + (size_t)25165824, WPK1, g1_bhh, HBUF);

    float* QH = HBUF;
    float* AH = HBUF + (size_t)64 * 256 * 512;

    // 4. BiDAF1: c=QH, q=AH -> ATT (set)
    {
        cwqw_kernel<<<32768, 64, 0, stream>>>(QH, AH, b1_w, CW, QW);
        smat_kernel<<<dim3(4, 4, 64), 256, 0, stream>>>(QH, AH, b1_w + 1024, b1_b, CW, QW, SMAT);
        softmax_kernel<<<16384, 64, 0, stream>>>(SMAT, RM);
        bb_kernel<<<64, 256, 0, stream>>>(RM, BBv);
        q2c_kernel<<<dim3(64, 4), 128, 0, stream>>>(BBv, QH, Q2C);
        fixup03<<<16384, 256, 0, stream>>>(QH, Q2C, ATT, 0);
        c2q_fixup<<<dim3(4, 8, 64), 256, 0, stream>>>(SMAT, AH, QH, ATT, 0);
    }

    // 5. GRU2 input gates: per dir, M=16384 N=768 K=2048, A fp32 / B bf16
    for (int d = 0; d < 2; d++) {
        gemm_a32b16<<<dim3(128, 6), 256, 0, stream>>>(
            ATT, WIH2B + (size_t)d * 1572864, g2_bih + d * 768,
            GI2B + (size_t)d * 12582912, 16384, 768, 2048);
    }
    // 6. GRU2 scan
    gru_scan_rreg<<<128, 512, 0, stream>>>(GI2B, GI2B + (size_t)12582912, WPK2, g2_bhh, AX2);

    // 7. BiDAF2: c=q=AX2 -> ATT (accumulate)
    {
        cwqw_kernel<<<32768, 64, 0, stream>>>(AX2, AX2, b2_w, CW, QW);
        smat_kernel<<<dim3(4, 4, 64), 256, 0, stream>>>(AX2, AX2, b2_w + 1024, b2_b, CW, QW, SMAT);
        softmax_kernel<<<16384, 64, 0, stream>>>(SMAT, RM);
        bb_kernel<<<64, 256, 0, stream>>>(RM, BBv);
        q2c_kernel<<<dim3(64, 4), 128, 0, stream>>>(BBv, AX2, Q2C);
        fixup03<<<16384, 256, 0, stream>>>(AX2, Q2C, ATT, 1);
        c2q_fixup<<<dim3(4, 8, 64), 256, 0, stream>>>(SMAT, AX2, AX2, ATT, 1);
    }

    // 8. rank reduce
    reduce1_kernel<<<dim3(32, 8), 256, 0, stream>>>(ATT, rank_w, PART);
    reduce2_kernel<<<1, 32, 0, stream>>>(PART, rank_b, out);
}

// Round 6
// 1399.454 us; speedup vs baseline: 1.2093x; 1.0563x over previous
//
#include <hip/hip_runtime.h>
#include <math.h>

#define LSEQ 256
#define HID 256
#define H2 512
#define H3 768
#define H8 2048

typedef __attribute__((ext_vector_type(8))) short short8;
typedef __attribute__((ext_vector_type(4))) float floatx4;

__device__ __forceinline__ unsigned short f2bf(float f) {
    unsigned int u = __float_as_uint(f);
    u = (u + 0x7FFFu + ((u >> 16) & 1u)) >> 16;
    return (unsigned short)u;
}
__device__ __forceinline__ float bf2f(unsigned short h) {
    return __uint_as_float(((unsigned int)h) << 16);
}
__device__ __forceinline__ float fsig(float x) {
    return __builtin_amdgcn_rcpf(1.f + __expf(-x));
}
__device__ __forceinline__ float ftanh(float x) {
    return __builtin_fmaf(2.f, __builtin_amdgcn_rcpf(1.f + __expf(-2.f * x)), -1.f);
}
// split fp32 -> (hi,lo) bf16 pair; hi+lo reproduces x to ~2^-17 rel
__device__ __forceinline__ void bfsplit(float x, unsigned short& hi, unsigned short& lo) {
    hi = f2bf(x);
    lo = f2bf(x - bf2f(hi));
}

// ---------------- embed (bf16 out) ----------------
__global__ void embed_kernel(const int* __restrict__ question,
                             const int* __restrict__ article,
                             const float* __restrict__ emb,
                             unsigned short* __restrict__ xemb) {
    int gid = blockIdx.x * 256 + threadIdx.x;   // 128*256*256
    int d = gid & 255;
    int rl = gid >> 8;
    int l = rl & 255;
    int stream = rl >> 8;
    int id;
    if (stream < 64) {
        int b = stream >> 3, o = (stream & 7) >> 1;
        id = question[(b * 4 + o) * 256 + l];
    } else {
        id = article[(stream - 64) * 256 + l];
    }
    xemb[(size_t)gid] = f2bf(emb[(size_t)id * 256 + d]);
}

// ---------------- vectorized fp32 -> bf16 pack (8 elems/thread) ----------------
__global__ void pack_bf8(const float* __restrict__ src, unsigned short* __restrict__ dst, int n8) {
    int i = blockIdx.x * 256 + threadIdx.x;
    if (i >= n8) return;
    float4 a = ((const float4*)src)[2 * i];
    float4 b = ((const float4*)src)[2 * i + 1];
    uint4 o;
    o.x = (unsigned int)f2bf(a.x) | ((unsigned int)f2bf(a.y) << 16);
    o.y = (unsigned int)f2bf(a.z) | ((unsigned int)f2bf(a.w) << 16);
    o.z = (unsigned int)f2bf(b.x) | ((unsigned int)f2bf(b.y) << 16);
    o.w = (unsigned int)f2bf(b.z) | ((unsigned int)f2bf(b.w) << 16);
    ((uint4*)dst)[i] = o;
}

// ---------------- MFMA GEMM: A bf16, B bf16 (both pre-packed) ----------------
__global__ __launch_bounds__(256)
void gemm_a16b16(const unsigned short* __restrict__ A, const unsigned short* __restrict__ B,
                 const float* __restrict__ bias, unsigned short* __restrict__ C,
                 int M, int N, int K) {
    __shared__ unsigned short At[128][40];
    __shared__ unsigned short Bt[128][40];
    int tid = threadIdx.x;
    int m0 = blockIdx.x * 128, n0 = blockIdx.y * 128;
    int l = tid & 63, w = tid >> 6;
    int wm = (w & 1) * 64, wn = (w >> 1) * 64;
    int lr = l & 15, koff = (l >> 4) * 8;
    int srow = tid >> 1, scol = (tid & 1) * 16;
    floatx4 acc[4][4];
#pragma unroll
    for (int i = 0; i < 4; i++)
#pragma unroll
        for (int j = 0; j < 4; j++) acc[i][j] = (floatx4){0.f, 0.f, 0.f, 0.f};
    for (int k0 = 0; k0 < K; k0 += 32) {
        const unsigned short* ap = A + (size_t)(m0 + srow) * K + k0 + scol;
        const unsigned short* bp = B + (size_t)(n0 + srow) * K + k0 + scol;
        uint4 a0 = *(const uint4*)(ap);
        uint4 a1 = *(const uint4*)(ap + 8);
        uint4 b0 = *(const uint4*)(bp);
        uint4 b1 = *(const uint4*)(bp + 8);
        __syncthreads();
        *(uint4*)&At[srow][scol]     = a0;
        *(uint4*)&At[srow][scol + 8] = a1;
        *(uint4*)&Bt[srow][scol]     = b0;
        *(uint4*)&Bt[srow][scol + 8] = b1;
        __syncthreads();
        short8 af[4], bf[4];
#pragma unroll
        for (int i = 0; i < 4; i++) {
            af[i] = *(const short8*)&At[wm + i * 16 + lr][koff];
            bf[i] = *(const short8*)&Bt[wn + i * 16 + lr][koff];
        }
#pragma unroll
        for (int i = 0; i < 4; i++)
#pragma unroll
            for (int j = 0; j < 4; j++)
                acc[i][j] = __builtin_amdgcn_mfma_f32_16x16x32_bf16(af[i], bf[j], acc[i][j], 0, 0, 0);
    }
    int quad = l >> 4;
#pragma unroll
    for (int i = 0; i < 4; i++) {
#pragma unroll
        for (int j = 0; j < 4; j++) {
            int n = n0 + wn + j * 16 + lr;
            float bs = bias[n];
#pragma unroll
            for (int r = 0; r < 4; r++) {
                int m = m0 + wm + i * 16 + quad * 4 + r;
                C[(size_t)m * N + n] = f2bf(acc[i][j][r] + bs);
            }
        }
    }
}

// ---------------- MFMA GEMM: A fp32 (convert in-kernel), B bf16 pre-packed ----------------
__global__ __launch_bounds__(256)
void gemm_a32b16(const float* __restrict__ A, const unsigned short* __restrict__ B,
                 const float* __restrict__ bias, unsigned short* __restrict__ C,
                 int M, int N, int K) {
    __shared__ unsigned short At[128][40];
    __shared__ unsigned short Bt[128][40];
    int tid = threadIdx.x;
    int m0 = blockIdx.x * 128, n0 = blockIdx.y * 128;
    int l = tid & 63, w = tid >> 6;
    int wm = (w & 1) * 64, wn = (w >> 1) * 64;
    int lr = l & 15, koff = (l >> 4) * 8;
    int srow = tid >> 1, scol = (tid & 1) * 16;
    floatx4 acc[4][4];
#pragma unroll
    for (int i = 0; i < 4; i++)
#pragma unroll
        for (int j = 0; j < 4; j++) acc[i][j] = (floatx4){0.f, 0.f, 0.f, 0.f};
    for (int k0 = 0; k0 < K; k0 += 32) {
        const float* ap = A + (size_t)(m0 + srow) * K + k0 + scol;
        const unsigned short* bp = B + (size_t)(n0 + srow) * K + k0 + scol;
        float av[16];
        *(float4*)&av[0]  = *(const float4*)(ap);
        *(float4*)&av[4]  = *(const float4*)(ap + 4);
        *(float4*)&av[8]  = *(const float4*)(ap + 8);
        *(float4*)&av[12] = *(const float4*)(ap + 12);
        uint4 b0 = *(const uint4*)(bp);
        uint4 b1 = *(const uint4*)(bp + 8);
        unsigned int aw[8];
#pragma unroll
        for (int i = 0; i < 8; i++)
            aw[i] = (unsigned int)f2bf(av[2 * i]) | ((unsigned int)f2bf(av[2 * i + 1]) << 16);
        __syncthreads();
        *(uint4*)&At[srow][scol]     = *(uint4*)&aw[0];
        *(uint4*)&At[srow][scol + 8] = *(uint4*)&aw[4];
        *(uint4*)&Bt[srow][scol]     = b0;
        *(uint4*)&Bt[srow][scol + 8] = b1;
        __syncthreads();
        short8 af[4], bf[4];
#pragma unroll
        for (int i = 0; i < 4; i++) {
            af[i] = *(const short8*)&At[wm + i * 16 + lr][koff];
            bf[i] = *(const short8*)&Bt[wn + i * 16 + lr][koff];
        }
#pragma unroll
        for (int i = 0; i < 4; i++)
#pragma unroll
            for (int j = 0; j < 4; j++)
                acc[i][j] = __builtin_amdgcn_mfma_f32_16x16x32_bf16(af[i], bf[j], acc[i][j], 0, 0, 0);
    }
    int quad = l >> 4;
#pragma unroll
    for (int i = 0; i < 4; i++) {
#pragma unroll
        for (int j = 0; j < 4; j++) {
            int n = n0 + wn + j * 16 + lr;
            float bs = bias[n];
#pragma unroll
            for (int r = 0; r < 4; r++) {
                int m = m0 + wm + i * 16 + quad * 4 + r;
                C[(size_t)m * N + n] = f2bf(acc[i][j][r] + bs);
            }
        }
    }
}

// ---------------- GRU scan: 1 stream/block, whh in VGPRs, in-wave gates ----------------
__global__ __launch_bounds__(512, 2)
void gru_scan_rreg(const unsigned short* __restrict__ gi_f,
                   const unsigned short* __restrict__ gi_b,
                   const unsigned short* __restrict__ whh_bf,
                   const float* __restrict__ bhh,
                   float* __restrict__ out) {
    int blk = blockIdx.x;
    int d = blk & 1, s = blk >> 1;
    const unsigned short* gi_blk = (d ? gi_b : gi_f) + (size_t)s * LSEQ * H3;
    const unsigned short* wb = whh_bf + (size_t)d * H3 * HID;

    __shared__ __align__(16) unsigned short h_pack[2][256];  // double-buffered h (bf16)

    int tid = threadIdx.x;
    int lane = tid & 63, wave = tid >> 6;
    int lr = lane & 15, kq = lane >> 4;

    short8 bq[6][8];
#pragma unroll
    for (int nt = 0; nt < 6; nt++) {
        int row = (nt >> 1) * 256 + wave * 32 + (nt & 1) * 16 + lr;
        const unsigned short* wp = wb + (size_t)row * HID + kq * 8;
#pragma unroll
        for (int kt = 0; kt < 8; kt++)
            bq[nt][kt] = *(const short8*)(wp + kt * 32);
    }

    int hh0 = wave * 32 + lr, hh1 = hh0 + 16;
    float br0 = bhh[d * H3 + hh0],       br1 = bhh[d * H3 + hh1];
    float bz0 = bhh[d * H3 + 256 + hh0], bz1 = bhh[d * H3 + 256 + hh1];
    float bn0 = bhh[d * H3 + 512 + hh0], bn1 = bhh[d * H3 + 512 + hh1];

    int t0 = d ? (LSEQ - 1) : 0;
    int tstep = d ? -1 : 1;

    if (tid < 128) ((unsigned int*)h_pack[0])[tid] = 0;
    float hold0 = 0.f, hold1 = 0.f;

    unsigned short gr0, gz0, gn0, gr1, gz1, gn1;
    {
        const unsigned short* gp = gi_blk + (size_t)t0 * H3;
        gr0 = gp[hh0]; gz0 = gp[256 + hh0]; gn0 = gp[512 + hh0];
        gr1 = gp[hh1]; gz1 = gp[256 + hh1]; gn1 = gp[512 + hh1];
    }
    __syncthreads();

    int cur = 0, t = t0;
    for (int step = 0; step < LSEQ; ++step) {
        unsigned short nr0 = 0, nz0 = 0, nn0 = 0, nr1 = 0, nz1 = 0, nn1 = 0;
        if (step + 1 < LSEQ) {
            const unsigned short* gp = gi_blk + (size_t)(t + tstep) * H3;
            nr0 = gp[hh0]; nz0 = gp[256 + hh0]; nn0 = gp[512 + hh0];
            nr1 = gp[hh1]; nz1 = gp[256 + hh1]; nn1 = gp[512 + hh1];
        }
        floatx4 acc[6];
#pragma unroll
        for (int nt = 0; nt < 6; nt++) acc[nt] = (floatx4){0.f, 0.f, 0.f, 0.f};
#pragma unroll
        for (int kt = 0; kt < 8; kt++) {
            short8 av = *(const short8*)&h_pack[cur][kt * 32 + kq * 8];  // broadcast
#pragma unroll
            for (int nt = 0; nt < 6; nt++)
                acc[nt] = __builtin_amdgcn_mfma_f32_16x16x32_bf16(av, bq[nt][kt], acc[nt], 0, 0, 0);
        }
        float rg0 = fsig(bf2f(gr0) + acc[0][0] + br0);
        float rg1 = fsig(bf2f(gr1) + acc[1][0] + br1);
        float zg0 = fsig(bf2f(gz0) + acc[2][0] + bz0);
        float zg1 = fsig(bf2f(gz1) + acc[3][0] + bz1);
        float ng0 = ftanh(bf2f(gn0) + rg0 * (acc[4][0] + bn0));
        float ng1 = ftanh(bf2f(gn1) + rg1 * (acc[5][0] + bn1));
        float h0 = (1.f - zg0) * ng0 + zg0 * hold0;
        float h1 = (1.f - zg1) * ng1 + zg1 * hold1;
        hold0 = h0; hold1 = h1;
        int nxt = cur ^ 1;
        if (kq == 0) {
            h_pack[nxt][hh0] = f2bf(h0);
            h_pack[nxt][hh1] = f2bf(h1);
            float* op = out + ((size_t)s * LSEQ + t) * H2 + d * HID;
            op[hh0] = h0;
            op[hh1] = h1;
        }
        gr0 = nr0; gz0 = nz0; gn0 = nn0;
        gr1 = nr1; gz1 = nz1; gn1 = nn1;
        __syncthreads();
        cur = nxt; t += tstep;
    }
}

// ---------------- bidaf helpers ----------------
__global__ void cwqw_kernel(const float* __restrict__ c, const float* __restrict__ q,
                            const float* __restrict__ w,
                            float* __restrict__ cw, float* __restrict__ qw) {
    int row = blockIdx.x;
    int lane = threadIdx.x;
    const float* src; const float* wv; float* dst; int r;
    if (row < 16384) { src = c; wv = w; dst = cw; r = row; }
    else { src = q; wv = w + 512; dst = qw; r = row - 16384; }
    const float* p = src + (size_t)r * H2;
    float acc = 0.f;
    for (int j = lane; j < H2; j += 64) acc += p[j] * wv[j];
    for (int off = 32; off; off >>= 1) acc += __shfl_down(acc, off);
    if (lane == 0) dst[r] = acc;
}

// smat via MFMA with split-bf16 (hi+lo) operands: fp32-quality scores.
// S[m][n] = sum_k (c[m][k]*w2[k]) * q[n][k]  + cw[m] + qw[n] + bsum
__global__ __launch_bounds__(256)
void smat_mfma(const float* __restrict__ c, const float* __restrict__ q,
               const float* __restrict__ w2, const float* __restrict__ bvec,
               const float* __restrict__ cw, const float* __restrict__ qw,
               float* __restrict__ smat) {
    __shared__ __align__(16) unsigned short Ah[128][40];
    __shared__ __align__(16) unsigned short Al[128][40];
    __shared__ __align__(16) unsigned short Bh[128][40];
    __shared__ __align__(16) unsigned short Bl[128][40];
    int b = blockIdx.z;
    int m0 = blockIdx.x * 128, n0 = blockIdx.y * 128;
    int tid = threadIdx.x;
    int l = tid & 63, w = tid >> 6;
    int wm = (w & 1) * 64, wn = (w >> 1) * 64;
    int lr = l & 15, koff = (l >> 4) * 8;
    int srow = tid >> 1, scol = (tid & 1) * 16;
    floatx4 acc[4][4];
#pragma unroll
    for (int i = 0; i < 4; i++)
#pragma unroll
        for (int j = 0; j < 4; j++) acc[i][j] = (floatx4){0.f, 0.f, 0.f, 0.f};
    const float* ap0 = c + (size_t)(b * 256 + m0 + srow) * H2 + scol;
    const float* bp0 = q + (size_t)(b * 256 + n0 + srow) * H2 + scol;
    for (int k0 = 0; k0 < H2; k0 += 32) {
        float av[16], bv[16], wv[16];
        *(float4*)&av[0]  = *(const float4*)(ap0 + k0);
        *(float4*)&av[4]  = *(const float4*)(ap0 + k0 + 4);
        *(float4*)&av[8]  = *(const float4*)(ap0 + k0 + 8);
        *(float4*)&av[12] = *(const float4*)(ap0 + k0 + 12);
        *(float4*)&bv[0]  = *(const float4*)(bp0 + k0);
        *(float4*)&bv[4]  = *(const float4*)(bp0 + k0 + 4);
        *(float4*)&bv[8]  = *(const float4*)(bp0 + k0 + 8);
        *(float4*)&bv[12] = *(const float4*)(bp0 + k0 + 12);
        *(float4*)&wv[0]  = *(const float4*)(w2 + k0 + scol);
        *(float4*)&wv[4]  = *(const float4*)(w2 + k0 + scol + 4);
        *(float4*)&wv[8]  = *(const float4*)(w2 + k0 + scol + 8);
        *(float4*)&wv[12] = *(const float4*)(w2 + k0 + scol + 12);
        unsigned int ahw[8], alw[8], bhw[8], blw[8];
#pragma unroll
        for (int j = 0; j < 8; j++) {
            float p0 = av[2 * j] * wv[2 * j], p1 = av[2 * j + 1] * wv[2 * j + 1];
            unsigned short h0, s0, h1, s1;
            bfsplit(p0, h0, s0); bfsplit(p1, h1, s1);
            ahw[j] = (unsigned int)h0 | ((unsigned int)h1 << 16);
            alw[j] = (unsigned int)s0 | ((unsigned int)s1 << 16);
            unsigned short g0, t0, g1, t1;
            bfsplit(bv[2 * j], g0, t0); bfsplit(bv[2 * j + 1], g1, t1);
            bhw[j] = (unsigned int)g0 | ((unsigned int)g1 << 16);
            blw[j] = (unsigned int)t0 | ((unsigned int)t1 << 16);
        }
        __syncthreads();
        *(uint4*)&Ah[srow][scol]     = *(uint4*)&ahw[0];
        *(uint4*)&Ah[srow][scol + 8] = *(uint4*)&ahw[4];
        *(uint4*)&Al[srow][scol]     = *(uint4*)&alw[0];
        *(uint4*)&Al[srow][scol + 8] = *(uint4*)&alw[4];
        *(uint4*)&Bh[srow][scol]     = *(uint4*)&bhw[0];
        *(uint4*)&Bh[srow][scol + 8] = *(uint4*)&bhw[4];
        *(uint4*)&Bl[srow][scol]     = *(uint4*)&blw[0];
        *(uint4*)&Bl[srow][scol + 8] = *(uint4*)&blw[4];
        __syncthreads();
        short8 afh[4], afl[4], bfh[4], bfl[4];
#pragma unroll
        for (int i = 0; i < 4; i++) {
            afh[i] = *(const short8*)&Ah[wm + i * 16 + lr][koff];
            afl[i] = *(const short8*)&Al[wm + i * 16 + lr][koff];
            bfh[i] = *(const short8*)&Bh[wn + i * 16 + lr][koff];
            bfl[i] = *(const short8*)&Bl[wn + i * 16 + lr][koff];
        }
#pragma unroll
        for (int i = 0; i < 4; i++)
#pragma unroll
            for (int j = 0; j < 4; j++) {
                acc[i][j] = __builtin_amdgcn_mfma_f32_16x16x32_bf16(afl[i], bfh[j], acc[i][j], 0, 0, 0);
                acc[i][j] = __builtin_amdgcn_mfma_f32_16x16x32_bf16(afh[i], bfl[j], acc[i][j], 0, 0, 0);
                acc[i][j] = __builtin_amdgcn_mfma_f32_16x16x32_bf16(afh[i], bfh[j], acc[i][j], 0, 0, 0);
            }
    }
    float bsum = bvec[0] + bvec[1] + bvec[2];
    int quad = l >> 4;
#pragma unroll
    for (int i = 0; i < 4; i++) {
#pragma unroll
        for (int j = 0; j < 4; j++) {
            int n = n0 + wn + j * 16 + lr;
            float qwv = qw[b * 256 + n] + bsum;
#pragma unroll
            for (int r = 0; r < 4; r++) {
                int m = m0 + wm + i * 16 + quad * 4 + r;
                smat[((size_t)(b * 256 + m)) * 256 + n] = acc[i][j][r] + cw[b * 256 + m] + qwv;
            }
        }
    }
}

__global__ void softmax_kernel(float* __restrict__ smat, float* __restrict__ rowmax) {
    int row = blockIdx.x;
    int lane = threadIdx.x;
    float* p = smat + (size_t)row * LSEQ;
    float v[4];
    float mx = -1e30f;
#pragma unroll
    for (int j = 0; j < 4; j++) { v[j] = p[lane + j * 64]; mx = fmaxf(mx, v[j]); }
    for (int off = 32; off; off >>= 1) mx = fmaxf(mx, __shfl_down(mx, off));
    mx = __shfl(mx, 0);
    float sum = 0.f;
#pragma unroll
    for (int j = 0; j < 4; j++) { v[j] = __expf(v[j] - mx); sum += v[j]; }
    for (int off = 32; off; off >>= 1) sum += __shfl_down(sum, off);
    sum = __shfl(sum, 0);
    float inv = 1.f / sum;
#pragma unroll
    for (int j = 0; j < 4; j++) p[lane + j * 64] = v[j] * inv;
    if (lane == 0) rowmax[row] = mx;
}

__global__ void bb_kernel(const float* __restrict__ rowmax, float* __restrict__ bb) {
    int b = blockIdx.x; int t = threadIdx.x;
    __shared__ float red[256];
    float v = rowmax[b * LSEQ + t];
    red[t] = v; __syncthreads();
    for (int s = 128; s; s >>= 1) { if (t < s) red[t] = fmaxf(red[t], red[t + s]); __syncthreads(); }
    float mx = red[0]; __syncthreads();
    float e = __expf(v - mx);
    red[t] = e; __syncthreads();
    for (int s = 128; s; s >>= 1) { if (t < s) red[t] += red[t + s]; __syncthreads(); }
    bb[b * LSEQ + t] = e / red[0];
}

// q2c: grid (64,4) x 128 thr; 4 independent accumulators break the add chain
__global__ void q2c_kernel(const float* __restrict__ bb, const float* __restrict__ c,
                           float* __restrict__ q2c) {
    int b = blockIdx.x;
    int d = blockIdx.y * 128 + threadIdx.x;
    const float* cb = c + (size_t)b * LSEQ * H2 + d;
    const float* bbp = bb + b * LSEQ;
    float a0 = 0.f, a1 = 0.f, a2 = 0.f, a3 = 0.f;
    for (int i = 0; i < LSEQ; i += 4) {
        a0 += bbp[i]     * cb[(size_t)i * H2];
        a1 += bbp[i + 1] * cb[(size_t)(i + 1) * H2];
        a2 += bbp[i + 2] * cb[(size_t)(i + 2) * H2];
        a3 += bbp[i + 3] * cb[(size_t)(i + 3) * H2];
    }
    q2c[b * H2 + d] = (a0 + a1) + (a2 + a3);
}

// c2q via MFMA split-bf16: C2Q[m][n] = sum_k amat[m][k] * q[k][n]; fused relu epilogue.
// B-tile (q^T) is transposed in LDS during staging.
__global__ __launch_bounds__(256)
void c2q_mfma(const float* __restrict__ amat, const float* __restrict__ q,
              const float* __restrict__ c, float* __restrict__ att, int add) {
    __shared__ __align__(16) unsigned short Ah[128][40];
    __shared__ __align__(16) unsigned short Al[128][40];
    __shared__ __align__(16) unsigned short Bh[128][40];
    __shared__ __align__(16) unsigned short Bl[128][40];
    int b = blockIdx.z;
    int m0 = blockIdx.x * 128, n0 = blockIdx.y * 128;
    int tid = threadIdx.x;
    int l = tid & 63, w = tid >> 6;
    int wm = (w & 1) * 64, wn = (w >> 1) * 64;
    int lr = l & 15, koff = (l >> 4) * 8;
    int srow = tid >> 1, scol = (tid & 1) * 16;
    int bn = tid & 127, bkh = tid >> 7;           // B-stage: column n0+bn, k-half bkh
    floatx4 acc[4][4];
#pragma unroll
    for (int i = 0; i < 4; i++)
#pragma unroll
        for (int j = 0; j < 4; j++) acc[i][j] = (floatx4){0.f, 0.f, 0.f, 0.f};
    for (int k0 = 0; k0 < LSEQ; k0 += 32) {
        // A: amat[m][k], row-major
        float av[16];
        const float* ap = amat + (size_t)(b * 256 + m0 + srow) * 256 + k0 + scol;
        *(float4*)&av[0]  = *(const float4*)(ap);
        *(float4*)&av[4]  = *(const float4*)(ap + 4);
        *(float4*)&av[8]  = *(const float4*)(ap + 8);
        *(float4*)&av[12] = *(const float4*)(ap + 12);
        // B: q[k][n] -> Bt[n][k] (transpose during staging; coalesced reads along n)
        float qv[16];
        const float* qp = q + (size_t)(b * 256 + k0 + bkh * 16) * H2 + n0 + bn;
#pragma unroll
        for (int j = 0; j < 16; j++) qv[j] = qp[(size_t)j * H2];
        unsigned int ahw[8], alw[8], bhw[8], blw[8];
#pragma unroll
        for (int j = 0; j < 8; j++) {
            unsigned short h0, s0, h1, s1;
            bfsplit(av[2 * j], h0, s0); bfsplit(av[2 * j + 1], h1, s1);
            ahw[j] = (unsigned int)h0 | ((unsigned int)h1 << 16);
            alw[j] = (unsigned int)s0 | ((unsigned int)s1 << 16);
            unsigned short g0, t0, g1, t1;
            bfsplit(qv[2 * j], g0, t0); bfsplit(qv[2 * j + 1], g1, t1);
            bhw[j] = (unsigned int)g0 | ((unsigned int)g1 << 16);
            blw[j] = (unsigned int)t0 | ((unsigned int)t1 << 16);
        }
        __syncthreads();
        *(uint4*)&Ah[srow][scol]         = *(uint4*)&ahw[0];
        *(uint4*)&Ah[srow][scol + 8]     = *(uint4*)&ahw[4];
        *(uint4*)&Al[srow][scol]         = *(uint4*)&alw[0];
        *(uint4*)&Al[srow][scol + 8]     = *(uint4*)&alw[4];
        *(uint4*)&Bh[bn][bkh * 16]       = *(uint4*)&bhw[0];
        *(uint4*)&Bh[bn][bkh * 16 + 8]   = *(uint4*)&bhw[4];
        *(uint4*)&Bl[bn][bkh * 16]       = *(uint4*)&blw[0];
        *(uint4*)&Bl[bn][bkh * 16 + 8]   = *(uint4*)&blw[4];
        __syncthreads();
        short8 afh[4], afl[4], bfh[4], bfl[4];
#pragma unroll
        for (int i = 0; i < 4; i++) {
            afh[i] = *(const short8*)&Ah[wm + i * 16 + lr][koff];
            afl[i] = *(const short8*)&Al[wm + i * 16 + lr][koff];
            bfh[i] = *(const short8*)&Bh[wn + i * 16 + lr][koff];
            bfl[i] = *(const short8*)&Bl[wn + i * 16 + lr][koff];
        }
#pragma unroll
        for (int i = 0; i < 4; i++)
#pragma unroll
            for (int j = 0; j < 4; j++) {
                acc[i][j] = __builtin_amdgcn_mfma_f32_16x16x32_bf16(afl[i], bfh[j], acc[i][j], 0, 0, 0);
                acc[i][j] = __builtin_amdgcn_mfma_f32_16x16x32_bf16(afh[i], bfl[j], acc[i][j], 0, 0, 0);
                acc[i][j] = __builtin_amdgcn_mfma_f32_16x16x32_bf16(afh[i], bfh[j], acc[i][j], 0, 0, 0);
            }
    }
    int quad = l >> 4;
#pragma unroll
    for (int i = 0; i < 4; i++) {
#pragma unroll
        for (int j = 0; j < 4; j++) {
            int n = n0 + wn + j * 16 + lr;
#pragma unroll
            for (int r = 0; r < 4; r++) {
                int m = m0 + wm + i * 16 + quad * 4 + r;
                size_t row = (size_t)b * 256 + m;
                float a = acc[i][j][r];
                float cv = c[row * H2 + n];
                float v1 = fmaxf(a, 0.f);
                float v2 = fmaxf(cv * a, 0.f);
                float* p1 = att + row * H8 + 512 + n;
                float* p2 = att + row * H8 + 1024 + n;
                if (add) { *p1 += v1; *p2 += v2; }
                else     { *p1 = v1;  *p2 = v2; }
            }
        }
    }
}

__global__ void fixup03(const float* __restrict__ c, const float* __restrict__ q2c,
                        float* __restrict__ att, int add) {
    int row = blockIdx.x;
    int t = threadIdx.x;
    int b = row >> 8;
    float* o = att + (size_t)row * H8;
#pragma unroll
    for (int rep = 0; rep < 2; rep++) {
        int d = t + rep * 256;
        float cv = c[(size_t)row * H2 + d];
        float qv = q2c[b * H2 + d];
        float v0 = fmaxf(cv, 0.f);
        float v3 = fmaxf(cv * qv, 0.f);
        if (add) { o[d] += v0; o[d + 1536] += v3; }
        else     { o[d]  = v0; o[d + 1536]  = v3; }
    }
}

// ---------------- final rank reduce ----------------
__global__ void reduce1_kernel(const float* __restrict__ s, const float* __restrict__ rw,
                               float* __restrict__ part) {
    int bo = blockIdx.x;
    int p = blockIdx.y;
    int t = threadIdx.x;
    const float* s0 = s + (size_t)(2 * bo) * 524288;
    const float* s1 = s0 + 524288;
    size_t base = (size_t)p * 65536;
    float acc = 0.f;
    for (int j = t; j < 65536; j += 256) {
        size_t m = base + j;
        acc += rw[m] * fmaxf(s0[m], s1[m]);
    }
    __shared__ float red[256];
    red[t] = acc; __syncthreads();
    for (int ss = 128; ss; ss >>= 1) { if (t < ss) red[t] += red[t + ss]; __syncthreads(); }
    if (t == 0) part[bo * 8 + p] = red[0];
}

__global__ void reduce2_kernel(const float* __restrict__ part, const float* __restrict__ rb,
                               float* __restrict__ out) {
    int t = threadIdx.x;
    float a = rb[0];
    for (int p = 0; p < 8; p++) a += part[t * 8 + p];
    out[t] = a;
}

extern "C" void kernel_launch(void* const* d_in, const int* in_sizes, int n_in,
                              void* d_out, int out_size, void* d_ws, size_t ws_size,
                              hipStream_t stream) {
    const int* question = (const int*)d_in[0];
    const int* article  = (const int*)d_in[1];
    const float* emb    = (const float*)d_in[2];
    const float* g1_wih = (const float*)d_in[3];
    const float* g1_whh = (const float*)d_in[4];
    const float* g1_bih = (const float*)d_in[5];
    const float* g1_bhh = (const float*)d_in[6];
    const float* g2_wih = (const float*)d_in[7];
    const float* g2_whh = (const float*)d_in[8];
    const float* g2_bih = (const float*)d_in[9];
    const float* g2_bhh = (const float*)d_in[10];
    const float* b1_w   = (const float*)d_in[11];
    const float* b1_b   = (const float*)d_in[12];
    const float* b2_w   = (const float*)d_in[13];
    const float* b2_b   = (const float*)d_in[14];
    const float* rank_w = (const float*)d_in[15];
    const float* rank_b = (const float*)d_in[16];
    float* ws = (float*)d_ws;
    float* out = (float*)d_out;

    // ---- workspace layout (float offsets; phase-liveness verified) ----
    // weights  [0, 2162688)
    // smallbuf [2162688, 2293760)
    // slot A   [2293760, 6488064):  XEMBB (P1-2) / SMAT (P4,P7)
    // slot A'  [2293760, 14876672): GI2B (P5-6)
    // HBUF     [6488064, 23265280): scan1 out (P3-4); head QH, tail AH
    // AX2      [14876672, 23265280): scan2 out (P6-7)
    // ATT      [25165824, 58720256): P4 -> end; GI1B (P2-3) aliases its head
    // NOTE: no bf16 ATT mirror — ATT+mirror+GI2B = 62.9M floats > 58.7M ws (R5 bug).
    unsigned short* WPK1  = (unsigned short*)(ws);
    unsigned short* WIH1B = (unsigned short*)(ws + 196608);
    unsigned short* WPK2  = (unsigned short*)(ws + 393216);
    unsigned short* WIH2B = (unsigned short*)(ws + 589824);
    float* CW   = ws + 2162688;
    float* QW   = ws + 2179072;
    float* RM   = ws + 2195456;
    float* BBv  = ws + 2211840;
    float* Q2C  = ws + 2228224;
    float* PART = ws + 2260992;
    unsigned short* XEMBB = (unsigned short*)(ws + 2293760);
    float*          SMAT  = ws + 2293760;
    unsigned short* GI2B  = (unsigned short*)(ws + 2293760);
    float*          HBUF  = ws + 6488064;
    float*          AX2   = ws + 14876672;
    float*          ATT   = ws + 25165824;
    unsigned short* GI1B  = (unsigned short*)(ws + 25165824);

    // 1. embed (bf16) + pack all weights to bf16
    embed_kernel<<<32768, 256, 0, stream>>>(question, article, emb, XEMBB);
    pack_bf8<<<192, 256, 0, stream>>>(g1_whh, WPK1, 49152);
    pack_bf8<<<192, 256, 0, stream>>>(g1_wih, WIH1B, 49152);
    pack_bf8<<<192, 256, 0, stream>>>(g2_whh, WPK2, 49152);
    pack_bf8<<<1536, 256, 0, stream>>>(g2_wih, WIH2B, 393216);

    // 2. GRU1 input gates: per dir, M=32768 N=768 K=256, all-bf16
    for (int d = 0; d < 2; d++) {
        gemm_a16b16<<<dim3(256, 6), 256, 0, stream>>>(
            XEMBB, WIH1B + (size_t)d * 196608, g1_bih + d * 768,
            GI1B + (size_t)d * 25165824, 32768, 768, 256);
    }
    // 3. GRU1 scan
    gru_scan_rreg<<<256, 512, 0, stream>>>(GI1B, GI1B + (size_t)25165824, WPK1, g1_bhh, HBUF);

    float* QH = HBUF;
    float* AH = HBUF + (size_t)64 * 256 * 512;

    // 4. BiDAF1: c=QH, q=AH -> ATT (set)
    {
        cwqw_kernel<<<32768, 64, 0, stream>>>(QH, AH, b1_w, CW, QW);
        smat_mfma<<<dim3(2, 2, 64), 256, 0, stream>>>(QH, AH, b1_w + 1024, b1_b, CW, QW, SMAT);
        softmax_kernel<<<16384, 64, 0, stream>>>(SMAT, RM);
        bb_kernel<<<64, 256, 0, stream>>>(RM, BBv);
        q2c_kernel<<<dim3(64, 4), 128, 0, stream>>>(BBv, QH, Q2C);
        fixup03<<<16384, 256, 0, stream>>>(QH, Q2C, ATT, 0);
        c2q_mfma<<<dim3(2, 4, 64), 256, 0, stream>>>(SMAT, AH, QH, ATT, 0);
    }

    // 5. GRU2 input gates: per dir, M=16384 N=768 K=2048, A fp32 / B bf16
    for (int d = 0; d < 2; d++) {
        gemm_a32b16<<<dim3(128, 6), 256, 0, stream>>>(
            ATT, WIH2B + (size_t)d * 1572864, g2_bih + d * 768,
            GI2B + (size_t)d * 12582912, 16384, 768, 2048);
    }
    // 6. GRU2 scan
    gru_scan_rreg<<<128, 512, 0, stream>>>(GI2B, GI2B + (size_t)12582912, WPK2, g2_bhh, AX2);

    // 7. BiDAF2: c=q=AX2 -> ATT (accumulate)
    {
        cwqw_kernel<<<32768, 64, 0, stream>>>(AX2, AX2, b2_w, CW, QW);
        smat_mfma<<<dim3(2, 2, 64), 256, 0, stream>>>(AX2, AX2, b2_w + 1024, b2_b, CW, QW, SMAT);
        softmax_kernel<<<16384, 64, 0, stream>>>(SMAT, RM);
        bb_kernel<<<64, 256, 0, stream>>>(RM, BBv);
        q2c_kernel<<<dim3(64, 4), 128, 0, stream>>>(BBv, AX2, Q2C);
        fixup03<<<16384, 256, 0, stream>>>(AX2, Q2C, ATT, 1);
        c2q_mfma<<<dim3(2, 4, 64), 256, 0, stream>>>(SMAT, AX2, AX2, ATT, 1);
    }

    // 8. rank reduce
    reduce1_kernel<<<dim3(32, 8), 256, 0, stream>>>(ATT, rank_w, PART);
    reduce2_kernel<<<1, 32, 0, stream>>>(PART, rank_b, out);
}

// Round 8
// 1359.876 us; speedup vs baseline: 1.2445x; 1.0291x over previous
//
#include <hip/hip_runtime.h>
#include <math.h>

#define LSEQ 256
#define HID 256
#define H2 512
#define H3 768
#define H8 2048

typedef __attribute__((ext_vector_type(8))) short short8;
typedef __attribute__((ext_vector_type(4))) float floatx4;

__device__ __forceinline__ unsigned short f2bf(float f) {
    unsigned int u = __float_as_uint(f);
    u = (u + 0x7FFFu + ((u >> 16) & 1u)) >> 16;
    return (unsigned short)u;
}
__device__ __forceinline__ float bf2f(unsigned short h) {
    return __uint_as_float(((unsigned int)h) << 16);
}
__device__ __forceinline__ float fsig(float x) {
    return __builtin_amdgcn_rcpf(1.f + __expf(-x));
}
__device__ __forceinline__ float ftanh(float x) {
    return __builtin_fmaf(2.f, __builtin_amdgcn_rcpf(1.f + __expf(-2.f * x)), -1.f);
}
// split fp32 -> (hi,lo) bf16 pair; hi+lo reproduces x to ~2^-17 rel
__device__ __forceinline__ void bfsplit(float x, unsigned short& hi, unsigned short& lo) {
    hi = f2bf(x);
    lo = f2bf(x - bf2f(hi));
}

// ---------------- embed (bf16 out) ----------------
__global__ void embed_kernel(const int* __restrict__ question,
                             const int* __restrict__ article,
                             const float* __restrict__ emb,
                             unsigned short* __restrict__ xemb) {
    int gid = blockIdx.x * 256 + threadIdx.x;   // 128*256*256
    int d = gid & 255;
    int rl = gid >> 8;
    int l = rl & 255;
    int stream = rl >> 8;
    int id;
    if (stream < 64) {
        int b = stream >> 3, o = (stream & 7) >> 1;
        id = question[(b * 4 + o) * 256 + l];
    } else {
        id = article[(stream - 64) * 256 + l];
    }
    xemb[(size_t)gid] = f2bf(emb[(size_t)id * 256 + d]);
}

// ---------------- vectorized fp32 -> bf16 pack (8 elems/thread) ----------------
__global__ void pack_bf8(const float* __restrict__ src, unsigned short* __restrict__ dst, int n8) {
    int i = blockIdx.x * 256 + threadIdx.x;
    if (i >= n8) return;
    float4 a = ((const float4*)src)[2 * i];
    float4 b = ((const float4*)src)[2 * i + 1];
    uint4 o;
    o.x = (unsigned int)f2bf(a.x) | ((unsigned int)f2bf(a.y) << 16);
    o.y = (unsigned int)f2bf(a.z) | ((unsigned int)f2bf(a.w) << 16);
    o.z = (unsigned int)f2bf(b.x) | ((unsigned int)f2bf(b.y) << 16);
    o.w = (unsigned int)f2bf(b.z) | ((unsigned int)f2bf(b.w) << 16);
    ((uint4*)dst)[i] = o;
}

// ---------------- MFMA GEMM, both GRU dirs fused: A bf16 [M][K], B bf16 [1536][K] ----
// N = 1536 (dir0 rows 0..767, dir1 rows 768..1535). C split at n=768 into C0/C1
// (row stride 768), output row = mbase + m. bias flat [1536].
__global__ __launch_bounds__(256)
void gemm_2dir(const unsigned short* __restrict__ A, const unsigned short* __restrict__ B,
               const float* __restrict__ bias, unsigned short* __restrict__ C0,
               unsigned short* __restrict__ C1, int mbase, int K) {
    __shared__ unsigned short At[128][40];
    __shared__ unsigned short Bt[128][40];
    int tid = threadIdx.x;
    int m0 = blockIdx.x * 128, n0 = blockIdx.y * 128;
    int l = tid & 63, w = tid >> 6;
    int wm = (w & 1) * 64, wn = (w >> 1) * 64;
    int lr = l & 15, koff = (l >> 4) * 8;
    int srow = tid >> 1, scol = (tid & 1) * 16;
    floatx4 acc[4][4];
#pragma unroll
    for (int i = 0; i < 4; i++)
#pragma unroll
        for (int j = 0; j < 4; j++) acc[i][j] = (floatx4){0.f, 0.f, 0.f, 0.f};
    for (int k0 = 0; k0 < K; k0 += 32) {
        const unsigned short* ap = A + (size_t)(m0 + srow) * K + k0 + scol;
        const unsigned short* bp = B + (size_t)(n0 + srow) * K + k0 + scol;
        uint4 a0 = *(const uint4*)(ap);
        uint4 a1 = *(const uint4*)(ap + 8);
        uint4 b0 = *(const uint4*)(bp);
        uint4 b1 = *(const uint4*)(bp + 8);
        __syncthreads();
        *(uint4*)&At[srow][scol]     = a0;
        *(uint4*)&At[srow][scol + 8] = a1;
        *(uint4*)&Bt[srow][scol]     = b0;
        *(uint4*)&Bt[srow][scol + 8] = b1;
        __syncthreads();
        short8 af[4], bf[4];
#pragma unroll
        for (int i = 0; i < 4; i++) {
            af[i] = *(const short8*)&At[wm + i * 16 + lr][koff];
            bf[i] = *(const short8*)&Bt[wn + i * 16 + lr][koff];
        }
#pragma unroll
        for (int i = 0; i < 4; i++)
#pragma unroll
            for (int j = 0; j < 4; j++)
                acc[i][j] = __builtin_amdgcn_mfma_f32_16x16x32_bf16(af[i], bf[j], acc[i][j], 0, 0, 0);
    }
    int quad = l >> 4;
#pragma unroll
    for (int i = 0; i < 4; i++) {
#pragma unroll
        for (int j = 0; j < 4; j++) {
            int n = n0 + wn + j * 16 + lr;
            float bs = bias[n];
            unsigned short* dst = (n < 768) ? C0 : C1;
            int nn = (n < 768) ? n : n - 768;   // R7 bug: was n & 767 (768 != pow2)
#pragma unroll
            for (int r = 0; r < 4; r++) {
                int m = mbase + m0 + wm + i * 16 + quad * 4 + r;
                dst[(size_t)m * 768 + nn] = f2bf(acc[i][j][r] + bs);
            }
        }
    }
}

// ---------------- GRU scan: 1 stream/block, whh in VGPRs, in-wave gates ----------------
__global__ __launch_bounds__(512, 2)
void gru_scan_rreg(const unsigned short* __restrict__ gi_f,
                   const unsigned short* __restrict__ gi_b,
                   const unsigned short* __restrict__ whh_bf,
                   const float* __restrict__ bhh,
                   float* __restrict__ out) {
    int blk = blockIdx.x;
    int d = blk & 1, s = blk >> 1;
    const unsigned short* gi_blk = (d ? gi_b : gi_f) + (size_t)s * LSEQ * H3;
    const unsigned short* wb = whh_bf + (size_t)d * H3 * HID;

    __shared__ __align__(16) unsigned short h_pack[2][256];  // double-buffered h (bf16)

    int tid = threadIdx.x;
    int lane = tid & 63, wave = tid >> 6;
    int lr = lane & 15, kq = lane >> 4;

    short8 bq[6][8];
#pragma unroll
    for (int nt = 0; nt < 6; nt++) {
        int row = (nt >> 1) * 256 + wave * 32 + (nt & 1) * 16 + lr;
        const unsigned short* wp = wb + (size_t)row * HID + kq * 8;
#pragma unroll
        for (int kt = 0; kt < 8; kt++)
            bq[nt][kt] = *(const short8*)(wp + kt * 32);
    }

    int hh0 = wave * 32 + lr, hh1 = hh0 + 16;
    float br0 = bhh[d * H3 + hh0],       br1 = bhh[d * H3 + hh1];
    float bz0 = bhh[d * H3 + 256 + hh0], bz1 = bhh[d * H3 + 256 + hh1];
    float bn0 = bhh[d * H3 + 512 + hh0], bn1 = bhh[d * H3 + 512 + hh1];

    int t0 = d ? (LSEQ - 1) : 0;
    int tstep = d ? -1 : 1;

    if (tid < 128) ((unsigned int*)h_pack[0])[tid] = 0;
    float hold0 = 0.f, hold1 = 0.f;

    unsigned short gr0, gz0, gn0, gr1, gz1, gn1;
    {
        const unsigned short* gp = gi_blk + (size_t)t0 * H3;
        gr0 = gp[hh0]; gz0 = gp[256 + hh0]; gn0 = gp[512 + hh0];
        gr1 = gp[hh1]; gz1 = gp[256 + hh1]; gn1 = gp[512 + hh1];
    }
    __syncthreads();

    int cur = 0, t = t0;
    for (int step = 0; step < LSEQ; ++step) {
        unsigned short nr0 = 0, nz0 = 0, nn0 = 0, nr1 = 0, nz1 = 0, nn1 = 0;
        if (step + 1 < LSEQ) {
            const unsigned short* gp = gi_blk + (size_t)(t + tstep) * H3;
            nr0 = gp[hh0]; nz0 = gp[256 + hh0]; nn0 = gp[512 + hh0];
            nr1 = gp[hh1]; nz1 = gp[256 + hh1]; nn1 = gp[512 + hh1];
        }
        floatx4 acc[6];
#pragma unroll
        for (int nt = 0; nt < 6; nt++) acc[nt] = (floatx4){0.f, 0.f, 0.f, 0.f};
#pragma unroll
        for (int kt = 0; kt < 8; kt++) {
            short8 av = *(const short8*)&h_pack[cur][kt * 32 + kq * 8];  // broadcast
#pragma unroll
            for (int nt = 0; nt < 6; nt++)
                acc[nt] = __builtin_amdgcn_mfma_f32_16x16x32_bf16(av, bq[nt][kt], acc[nt], 0, 0, 0);
        }
        float rg0 = fsig(bf2f(gr0) + acc[0][0] + br0);
        float rg1 = fsig(bf2f(gr1) + acc[1][0] + br1);
        float zg0 = fsig(bf2f(gz0) + acc[2][0] + bz0);
        float zg1 = fsig(bf2f(gz1) + acc[3][0] + bz1);
        float ng0 = ftanh(bf2f(gn0) + rg0 * (acc[4][0] + bn0));
        float ng1 = ftanh(bf2f(gn1) + rg1 * (acc[5][0] + bn1));
        float h0 = (1.f - zg0) * ng0 + zg0 * hold0;
        float h1 = (1.f - zg1) * ng1 + zg1 * hold1;
        hold0 = h0; hold1 = h1;
        int nxt = cur ^ 1;
        if (kq == 0) {
            h_pack[nxt][hh0] = f2bf(h0);
            h_pack[nxt][hh1] = f2bf(h1);
            float* op = out + ((size_t)s * LSEQ + t) * H2 + d * HID;
            op[hh0] = h0;
            op[hh1] = h1;
        }
        gr0 = nr0; gz0 = nz0; gn0 = nn0;
        gr1 = nr1; gz1 = nz1; gn1 = nn1;
        __syncthreads();
        cur = nxt; t += tstep;
    }
}

// ---------------- bidaf helpers ----------------
__global__ void cwqw_kernel(const float* __restrict__ c, const float* __restrict__ q,
                            const float* __restrict__ w,
                            float* __restrict__ cw, float* __restrict__ qw) {
    int row = blockIdx.x;
    int lane = threadIdx.x;
    const float* src; const float* wv; float* dst; int r;
    if (row < 16384) { src = c; wv = w; dst = cw; r = row; }
    else { src = q; wv = w + 512; dst = qw; r = row - 16384; }
    const float* p = src + (size_t)r * H2;
    float acc = 0.f;
    for (int j = lane; j < H2; j += 64) acc += p[j] * wv[j];
    for (int off = 32; off; off >>= 1) acc += __shfl_down(acc, off);
    if (lane == 0) dst[r] = acc;
}

// smat via MFMA with split-bf16 (hi+lo) operands: fp32-quality scores.
// S[m][n] = sum_k (c[m][k]*w2[k]) * q[n][k]  + cw[m] + qw[n] + bsum
__global__ __launch_bounds__(256)
void smat_mfma(const float* __restrict__ c, const float* __restrict__ q,
               const float* __restrict__ w2, const float* __restrict__ bvec,
               const float* __restrict__ cw, const float* __restrict__ qw,
               float* __restrict__ smat) {
    __shared__ __align__(16) unsigned short Ah[128][40];
    __shared__ __align__(16) unsigned short Al[128][40];
    __shared__ __align__(16) unsigned short Bh[128][40];
    __shared__ __align__(16) unsigned short Bl[128][40];
    int b = blockIdx.z;
    int m0 = blockIdx.x * 128, n0 = blockIdx.y * 128;
    int tid = threadIdx.x;
    int l = tid & 63, w = tid >> 6;
    int wm = (w & 1) * 64, wn = (w >> 1) * 64;
    int lr = l & 15, koff = (l >> 4) * 8;
    int srow = tid >> 1, scol = (tid & 1) * 16;
    floatx4 acc[4][4];
#pragma unroll
    for (int i = 0; i < 4; i++)
#pragma unroll
        for (int j = 0; j < 4; j++) acc[i][j] = (floatx4){0.f, 0.f, 0.f, 0.f};
    const float* ap0 = c + (size_t)(b * 256 + m0 + srow) * H2 + scol;
    const float* bp0 = q + (size_t)(b * 256 + n0 + srow) * H2 + scol;
    for (int k0 = 0; k0 < H2; k0 += 32) {
        float av[16], bv[16], wv[16];
        *(float4*)&av[0]  = *(const float4*)(ap0 + k0);
        *(float4*)&av[4]  = *(const float4*)(ap0 + k0 + 4);
        *(float4*)&av[8]  = *(const float4*)(ap0 + k0 + 8);
        *(float4*)&av[12] = *(const float4*)(ap0 + k0 + 12);
        *(float4*)&bv[0]  = *(const float4*)(bp0 + k0);
        *(float4*)&bv[4]  = *(const float4*)(bp0 + k0 + 4);
        *(float4*)&bv[8]  = *(const float4*)(bp0 + k0 + 8);
        *(float4*)&bv[12] = *(const float4*)(bp0 + k0 + 12);
        *(float4*)&wv[0]  = *(const float4*)(w2 + k0 + scol);
        *(float4*)&wv[4]  = *(const float4*)(w2 + k0 + scol + 4);
        *(float4*)&wv[8]  = *(const float4*)(w2 + k0 + scol + 8);
        *(float4*)&wv[12] = *(const float4*)(w2 + k0 + scol + 12);
        unsigned int ahw[8], alw[8], bhw[8], blw[8];
#pragma unroll
        for (int j = 0; j < 8; j++) {
            float p0 = av[2 * j] * wv[2 * j], p1 = av[2 * j + 1] * wv[2 * j + 1];
            unsigned short h0, s0, h1, s1;
            bfsplit(p0, h0, s0); bfsplit(p1, h1, s1);
            ahw[j] = (unsigned int)h0 | ((unsigned int)h1 << 16);
            alw[j] = (unsigned int)s0 | ((unsigned int)s1 << 16);
            unsigned short g0, t0, g1, t1;
            bfsplit(bv[2 * j], g0, t0); bfsplit(bv[2 * j + 1], g1, t1);
            bhw[j] = (unsigned int)g0 | ((unsigned int)g1 << 16);
            blw[j] = (unsigned int)t0 | ((unsigned int)t1 << 16);
        }
        __syncthreads();
        *(uint4*)&Ah[srow][scol]     = *(uint4*)&ahw[0];
        *(uint4*)&Ah[srow][scol + 8] = *(uint4*)&ahw[4];
        *(uint4*)&Al[srow][scol]     = *(uint4*)&alw[0];
        *(uint4*)&Al[srow][scol + 8] = *(uint4*)&alw[4];
        *(uint4*)&Bh[srow][scol]     = *(uint4*)&bhw[0];
        *(uint4*)&Bh[srow][scol + 8] = *(uint4*)&bhw[4];
        *(uint4*)&Bl[srow][scol]     = *(uint4*)&blw[0];
        *(uint4*)&Bl[srow][scol + 8] = *(uint4*)&blw[4];
        __syncthreads();
        short8 afh[4], afl[4], bfh[4], bfl[4];
#pragma unroll
        for (int i = 0; i < 4; i++) {
            afh[i] = *(const short8*)&Ah[wm + i * 16 + lr][koff];
            afl[i] = *(const short8*)&Al[wm + i * 16 + lr][koff];
            bfh[i] = *(const short8*)&Bh[wn + i * 16 + lr][koff];
            bfl[i] = *(const short8*)&Bl[wn + i * 16 + lr][koff];
        }
#pragma unroll
        for (int i = 0; i < 4; i++)
#pragma unroll
            for (int j = 0; j < 4; j++) {
                acc[i][j] = __builtin_amdgcn_mfma_f32_16x16x32_bf16(afl[i], bfh[j], acc[i][j], 0, 0, 0);
                acc[i][j] = __builtin_amdgcn_mfma_f32_16x16x32_bf16(afh[i], bfl[j], acc[i][j], 0, 0, 0);
                acc[i][j] = __builtin_amdgcn_mfma_f32_16x16x32_bf16(afh[i], bfh[j], acc[i][j], 0, 0, 0);
            }
    }
    float bsum = bvec[0] + bvec[1] + bvec[2];
    int quad = l >> 4;
#pragma unroll
    for (int i = 0; i < 4; i++) {
#pragma unroll
        for (int j = 0; j < 4; j++) {
            int n = n0 + wn + j * 16 + lr;
            float qwv = qw[b * 256 + n] + bsum;
#pragma unroll
            for (int r = 0; r < 4; r++) {
                int m = m0 + wm + i * 16 + quad * 4 + r;
                smat[((size_t)(b * 256 + m)) * 256 + n] = acc[i][j][r] + cw[b * 256 + m] + qwv;
            }
        }
    }
}

__global__ void softmax_kernel(float* __restrict__ smat, float* __restrict__ rowmax) {
    int row = blockIdx.x;
    int lane = threadIdx.x;
    float* p = smat + (size_t)row * LSEQ;
    float v[4];
    float mx = -1e30f;
#pragma unroll
    for (int j = 0; j < 4; j++) { v[j] = p[lane + j * 64]; mx = fmaxf(mx, v[j]); }
    for (int off = 32; off; off >>= 1) mx = fmaxf(mx, __shfl_down(mx, off));
    mx = __shfl(mx, 0);
    float sum = 0.f;
#pragma unroll
    for (int j = 0; j < 4; j++) { v[j] = __expf(v[j] - mx); sum += v[j]; }
    for (int off = 32; off; off >>= 1) sum += __shfl_down(sum, off);
    sum = __shfl(sum, 0);
    float inv = 1.f / sum;
#pragma unroll
    for (int j = 0; j < 4; j++) p[lane + j * 64] = v[j] * inv;
    if (lane == 0) rowmax[row] = mx;
}

__global__ void bb_kernel(const float* __restrict__ rowmax, float* __restrict__ bb) {
    int b = blockIdx.x; int t = threadIdx.x;
    __shared__ float red[256];
    float v = rowmax[b * LSEQ + t];
    red[t] = v; __syncthreads();
    for (int s = 128; s; s >>= 1) { if (t < s) red[t] = fmaxf(red[t], red[t + s]); __syncthreads(); }
    float mx = red[0]; __syncthreads();
    float e = __expf(v - mx);
    red[t] = e; __syncthreads();
    for (int s = 128; s; s >>= 1) { if (t < s) red[t] += red[t + s]; __syncthreads(); }
    bb[b * LSEQ + t] = e / red[0];
}

// q2c: grid (64,4) x 128 thr; 4 independent accumulators break the add chain
__global__ void q2c_kernel(const float* __restrict__ bb, const float* __restrict__ c,
                           float* __restrict__ q2c) {
    int b = blockIdx.x;
    int d = blockIdx.y * 128 + threadIdx.x;
    const float* cb = c + (size_t)b * LSEQ * H2 + d;
    const float* bbp = bb + b * LSEQ;
    float a0 = 0.f, a1 = 0.f, a2 = 0.f, a3 = 0.f;
    for (int i = 0; i < LSEQ; i += 4) {
        a0 += bbp[i]     * cb[(size_t)i * H2];
        a1 += bbp[i + 1] * cb[(size_t)(i + 1) * H2];
        a2 += bbp[i + 2] * cb[(size_t)(i + 2) * H2];
        a3 += bbp[i + 3] * cb[(size_t)(i + 3) * H2];
    }
    q2c[b * H2 + d] = (a0 + a1) + (a2 + a3);
}

// c2q via MFMA split-bf16 with FUSED fixup03 epilogue.
// C2Q[m][n] = sum_k amat[m][k] * q[k][n]; writes all four ATT quadrants for n in [0,512):
//   att[row][n]      = relu(c[row][n])
//   att[row][512+n]  = relu(c2q)
//   att[row][1024+n] = relu(c[row][n] * c2q)
//   att[row][1536+n] = relu(c[row][n] * q2c[b][n])
__global__ __launch_bounds__(256)
void c2q_fix_mfma(const float* __restrict__ amat, const float* __restrict__ q,
                  const float* __restrict__ c, const float* __restrict__ q2c,
                  float* __restrict__ att, int add) {
    __shared__ __align__(16) unsigned short Ah[128][40];
    __shared__ __align__(16) unsigned short Al[128][40];
    __shared__ __align__(16) unsigned short Bh[128][40];
    __shared__ __align__(16) unsigned short Bl[128][40];
    int b = blockIdx.z;
    int m0 = blockIdx.x * 128, n0 = blockIdx.y * 128;
    int tid = threadIdx.x;
    int l = tid & 63, w = tid >> 6;
    int wm = (w & 1) * 64, wn = (w >> 1) * 64;
    int lr = l & 15, koff = (l >> 4) * 8;
    int srow = tid >> 1, scol = (tid & 1) * 16;
    int bn = tid & 127, bkh = tid >> 7;           // B-stage: column n0+bn, k-half bkh
    floatx4 acc[4][4];
#pragma unroll
    for (int i = 0; i < 4; i++)
#pragma unroll
        for (int j = 0; j < 4; j++) acc[i][j] = (floatx4){0.f, 0.f, 0.f, 0.f};
    for (int k0 = 0; k0 < LSEQ; k0 += 32) {
        float av[16];
        const float* ap = amat + (size_t)(b * 256 + m0 + srow) * 256 + k0 + scol;
        *(float4*)&av[0]  = *(const float4*)(ap);
        *(float4*)&av[4]  = *(const float4*)(ap + 4);
        *(float4*)&av[8]  = *(const float4*)(ap + 8);
        *(float4*)&av[12] = *(const float4*)(ap + 12);
        float qv[16];
        const float* qp = q + (size_t)(b * 256 + k0 + bkh * 16) * H2 + n0 + bn;
#pragma unroll
        for (int j = 0; j < 16; j++) qv[j] = qp[(size_t)j * H2];
        unsigned int ahw[8], alw[8], bhw[8], blw[8];
#pragma unroll
        for (int j = 0; j < 8; j++) {
            unsigned short h0, s0, h1, s1;
            bfsplit(av[2 * j], h0, s0); bfsplit(av[2 * j + 1], h1, s1);
            ahw[j] = (unsigned int)h0 | ((unsigned int)h1 << 16);
            alw[j] = (unsigned int)s0 | ((unsigned int)s1 << 16);
            unsigned short g0, t0, g1, t1;
            bfsplit(qv[2 * j], g0, t0); bfsplit(qv[2 * j + 1], g1, t1);
            bhw[j] = (unsigned int)g0 | ((unsigned int)g1 << 16);
            blw[j] = (unsigned int)t0 | ((unsigned int)t1 << 16);
        }
        __syncthreads();
        *(uint4*)&Ah[srow][scol]         = *(uint4*)&ahw[0];
        *(uint4*)&Ah[srow][scol + 8]     = *(uint4*)&ahw[4];
        *(uint4*)&Al[srow][scol]         = *(uint4*)&alw[0];
        *(uint4*)&Al[srow][scol + 8]     = *(uint4*)&alw[4];
        *(uint4*)&Bh[bn][bkh * 16]       = *(uint4*)&bhw[0];
        *(uint4*)&Bh[bn][bkh * 16 + 8]   = *(uint4*)&bhw[4];
        *(uint4*)&Bl[bn][bkh * 16]       = *(uint4*)&blw[0];
        *(uint4*)&Bl[bn][bkh * 16 + 8]   = *(uint4*)&blw[4];
        __syncthreads();
        short8 afh[4], afl[4], bfh[4], bfl[4];
#pragma unroll
        for (int i = 0; i < 4; i++) {
            afh[i] = *(const short8*)&Ah[wm + i * 16 + lr][koff];
            afl[i] = *(const short8*)&Al[wm + i * 16 + lr][koff];
            bfh[i] = *(const short8*)&Bh[wn + i * 16 + lr][koff];
            bfl[i] = *(const short8*)&Bl[wn + i * 16 + lr][koff];
        }
#pragma unroll
        for (int i = 0; i < 4; i++)
#pragma unroll
            for (int j = 0; j < 4; j++) {
                acc[i][j] = __builtin_amdgcn_mfma_f32_16x16x32_bf16(afl[i], bfh[j], acc[i][j], 0, 0, 0);
                acc[i][j] = __builtin_amdgcn_mfma_f32_16x16x32_bf16(afh[i], bfl[j], acc[i][j], 0, 0, 0);
                acc[i][j] = __builtin_amdgcn_mfma_f32_16x16x32_bf16(afh[i], bfh[j], acc[i][j], 0, 0, 0);
            }
    }
    int quad = l >> 4;
#pragma unroll
    for (int i = 0; i < 4; i++) {
#pragma unroll
        for (int j = 0; j < 4; j++) {
            int n = n0 + wn + j * 16 + lr;
            float q2cv = q2c[b * H2 + n];
#pragma unroll
            for (int r = 0; r < 4; r++) {
                int m = m0 + wm + i * 16 + quad * 4 + r;
                size_t row = (size_t)b * 256 + m;
                float a = acc[i][j][r];
                float cv = c[row * H2 + n];
                float v0 = fmaxf(cv, 0.f);
                float v1 = fmaxf(a, 0.f);
                float v2 = fmaxf(cv * a, 0.f);
                float v3 = fmaxf(cv * q2cv, 0.f);
                float* p0 = att + row * H8 + n;
                float* p1 = p0 + 512;
                float* p2 = p0 + 1024;
                float* p3 = p0 + 1536;
                if (add) { *p0 += v0; *p1 += v1; *p2 += v2; *p3 += v3; }
                else     { *p0 = v0;  *p1 = v1;  *p2 = v2;  *p3 = v3; }
            }
        }
    }
}

// ---------------- final rank reduce ----------------
__global__ void reduce1_kernel(const float* __restrict__ s, const float* __restrict__ rw,
                               float* __restrict__ part) {
    int bo = blockIdx.x;
    int p = blockIdx.y;
    int t = threadIdx.x;
    const float* s0 = s + (size_t)(2 * bo) * 524288;
    const float* s1 = s0 + 524288;
    size_t base = (size_t)p * 65536;
    float acc = 0.f;
    for (int j = t; j < 65536; j += 256) {
        size_t m = base + j;
        acc += rw[m] * fmaxf(s0[m], s1[m]);
    }
    __shared__ float red[256];
    red[t] = acc; __syncthreads();
    for (int ss = 128; ss; ss >>= 1) { if (t < ss) red[t] += red[t + ss]; __syncthreads(); }
    if (t == 0) part[bo * 8 + p] = red[0];
}

__global__ void reduce2_kernel(const float* __restrict__ part, const float* __restrict__ rb,
                               float* __restrict__ out) {
    int t = threadIdx.x;
    float a = rb[0];
    for (int p = 0; p < 8; p++) a += part[t * 8 + p];
    out[t] = a;
}

extern "C" void kernel_launch(void* const* d_in, const int* in_sizes, int n_in,
                              void* d_out, int out_size, void* d_ws, size_t ws_size,
                              hipStream_t stream) {
    const int* question = (const int*)d_in[0];
    const int* article  = (const int*)d_in[1];
    const float* emb    = (const float*)d_in[2];
    const float* g1_wih = (const float*)d_in[3];
    const float* g1_whh = (const float*)d_in[4];
    const float* g1_bih = (const float*)d_in[5];
    const float* g1_bhh = (const float*)d_in[6];
    const float* g2_wih = (const float*)d_in[7];
    const float* g2_whh = (const float*)d_in[8];
    const float* g2_bih = (const float*)d_in[9];
    const float* g2_bhh = (const float*)d_in[10];
    const float* b1_w   = (const float*)d_in[11];
    const float* b1_b   = (const float*)d_in[12];
    const float* b2_w   = (const float*)d_in[13];
    const float* b2_b   = (const float*)d_in[14];
    const float* rank_w = (const float*)d_in[15];
    const float* rank_b = (const float*)d_in[16];
    float* ws = (float*)d_ws;
    float* out = (float*)d_out;

    // ---- workspace layout (float offsets; phase-liveness verified) ----
    // weights  [0, 2162688)
    // smallbuf [2162688, 2293760)
    // slot A   [2293760, 6488064):  XEMBB (P1-2) / SMAT (P4,P7)
    // slot A'  [2293760, 14876672): GI2B (P5-6)
    // HBUF     [6488064, 23265280): scan1 out (P3-4); head QH, tail AH
    // ATTBH    [14876672, 23265280): half-M bf16 ATT mirror (P5 only, 8.39M fl OK)
    // AX2      [14876672, 23265280): scan2 out (P6-7)
    // ATT      [25165824, 58720256): P4 -> end; GI1B (P2-3) aliases its head
    unsigned short* WPK1  = (unsigned short*)(ws);
    unsigned short* WIH1B = (unsigned short*)(ws + 196608);
    unsigned short* WPK2  = (unsigned short*)(ws + 393216);
    unsigned short* WIH2B = (unsigned short*)(ws + 589824);
    float* CW   = ws + 2162688;
    float* QW   = ws + 2179072;
    float* RM   = ws + 2195456;
    float* BBv  = ws + 2211840;
    float* Q2C  = ws + 2228224;
    float* PART = ws + 2260992;
    unsigned short* XEMBB = (unsigned short*)(ws + 2293760);
    float*          SMAT  = ws + 2293760;
    unsigned short* GI2B  = (unsigned short*)(ws + 2293760);
    float*          HBUF  = ws + 6488064;
    unsigned short* ATTBH = (unsigned short*)(ws + 14876672);
    float*          AX2   = ws + 14876672;
    float*          ATT   = ws + 25165824;
    unsigned short* GI1B  = (unsigned short*)(ws + 25165824);

    // 1. embed (bf16) + pack all weights to bf16
    embed_kernel<<<32768, 256, 0, stream>>>(question, article, emb, XEMBB);
    pack_bf8<<<192, 256, 0, stream>>>(g1_whh, WPK1, 49152);
    pack_bf8<<<192, 256, 0, stream>>>(g1_wih, WIH1B, 49152);
    pack_bf8<<<192, 256, 0, stream>>>(g2_whh, WPK2, 49152);
    pack_bf8<<<1536, 256, 0, stream>>>(g2_wih, WIH2B, 393216);

    // 2. GRU1 input gates, both dirs fused: M=32768 N=1536 K=256
    gemm_2dir<<<dim3(256, 12), 256, 0, stream>>>(
        XEMBB, WIH1B, g1_bih, GI1B, GI1B + (size_t)25165824, 0, 256);
    // 3. GRU1 scan
    gru_scan_rreg<<<256, 512, 0, stream>>>(GI1B, GI1B + (size_t)25165824, WPK1, g1_bhh, HBUF);

    float* QH = HBUF;
    float* AH = HBUF + (size_t)64 * 256 * 512;

    // 4. BiDAF1: c=QH, q=AH -> ATT (set); fixup03 fused into c2q
    {
        cwqw_kernel<<<32768, 64, 0, stream>>>(QH, AH, b1_w, CW, QW);
        smat_mfma<<<dim3(2, 2, 64), 256, 0, stream>>>(QH, AH, b1_w + 1024, b1_b, CW, QW, SMAT);
        softmax_kernel<<<16384, 64, 0, stream>>>(SMAT, RM);
        bb_kernel<<<64, 256, 0, stream>>>(RM, BBv);
        q2c_kernel<<<dim3(64, 4), 128, 0, stream>>>(BBv, QH, Q2C);
        c2q_fix_mfma<<<dim3(2, 4, 64), 256, 0, stream>>>(SMAT, AH, QH, Q2C, ATT, 0);
    }

    // 5. GRU2 input gates: half-M buffered ATT->bf16 pack + fused-dir all-bf16 GEMM
    for (int half = 0; half < 2; half++) {
        pack_bf8<<<8192, 256, 0, stream>>>(ATT + (size_t)half * 16777216, ATTBH, 2097152);
        gemm_2dir<<<dim3(64, 12), 256, 0, stream>>>(
            ATTBH, WIH2B, g2_bih, GI2B, GI2B + (size_t)12582912, half * 8192, 2048);
    }
    // 6. GRU2 scan (AX2 overwrites dead ATTBH)
    gru_scan_rreg<<<128, 512, 0, stream>>>(GI2B, GI2B + (size_t)12582912, WPK2, g2_bhh, AX2);

    // 7. BiDAF2: c=q=AX2 -> ATT (accumulate); fixup03 fused into c2q
    {
        cwqw_kernel<<<32768, 64, 0, stream>>>(AX2, AX2, b2_w, CW, QW);
        smat_mfma<<<dim3(2, 2, 64), 256, 0, stream>>>(AX2, AX2, b2_w + 1024, b2_b, CW, QW, SMAT);
        softmax_kernel<<<16384, 64, 0, stream>>>(SMAT, RM);
        bb_kernel<<<64, 256, 0, stream>>>(RM, BBv);
        q2c_kernel<<<dim3(64, 4), 128, 0, stream>>>(BBv, AX2, Q2C);
        c2q_fix_mfma<<<dim3(2, 4, 64), 256, 0, stream>>>(SMAT, AX2, AX2, Q2C, ATT, 1);
    }

    // 8. rank reduce
    reduce1_kernel<<<dim3(32, 8), 256, 0, stream>>>(ATT, rank_w, PART);
    reduce2_kernel<<<1, 32, 0, stream>>>(PART, rank_b, out);
}

// Round 9
// 1321.933 us; speedup vs baseline: 1.2802x; 1.0287x over previous
//
#include <hip/hip_runtime.h>
#include <math.h>

#define LSEQ 256
#define HID 256
#define H2 512
#define H3 768
#define H8 2048

typedef __attribute__((ext_vector_type(8))) short short8;
typedef __attribute__((ext_vector_type(4))) float floatx4;

__device__ __forceinline__ unsigned short f2bf(float f) {
    unsigned int u = __float_as_uint(f);
    u = (u + 0x7FFFu + ((u >> 16) & 1u)) >> 16;
    return (unsigned short)u;
}
__device__ __forceinline__ float bf2f(unsigned short h) {
    return __uint_as_float(((unsigned int)h) << 16);
}
__device__ __forceinline__ float fsig(float x) {
    return __builtin_amdgcn_rcpf(1.f + __expf(-x));
}
__device__ __forceinline__ float ftanh(float x) {
    return __builtin_fmaf(2.f, __builtin_amdgcn_rcpf(1.f + __expf(-2.f * x)), -1.f);
}
// split fp32 -> (hi,lo) bf16 pair; hi+lo reproduces x to ~2^-17 rel
__device__ __forceinline__ void bfsplit(float x, unsigned short& hi, unsigned short& lo) {
    hi = f2bf(x);
    lo = f2bf(x - bf2f(hi));
}
// async global->LDS 16B per lane: LDS dest = base + lane*16 (wave-uniform base)
__device__ __forceinline__ void gload_lds16(const void* g, void* l) {
    __builtin_amdgcn_global_load_lds(
        (const __attribute__((address_space(1))) unsigned int*)g,
        (__attribute__((address_space(3))) unsigned int*)l, 16, 0, 0);
}

// ---------------- embed (bf16 out) ----------------
__global__ void embed_kernel(const int* __restrict__ question,
                             const int* __restrict__ article,
                             const float* __restrict__ emb,
                             unsigned short* __restrict__ xemb) {
    int gid = blockIdx.x * 256 + threadIdx.x;   // 128*256*256
    int d = gid & 255;
    int rl = gid >> 8;
    int l = rl & 255;
    int stream = rl >> 8;
    int id;
    if (stream < 64) {
        int b = stream >> 3, o = (stream & 7) >> 1;
        id = question[(b * 4 + o) * 256 + l];
    } else {
        id = article[(stream - 64) * 256 + l];
    }
    xemb[(size_t)gid] = f2bf(emb[(size_t)id * 256 + d]);
}

// ---------------- vectorized fp32 -> bf16 pack (8 elems/thread) ----------------
__global__ void pack_bf8(const float* __restrict__ src, unsigned short* __restrict__ dst, int n8) {
    int i = blockIdx.x * 256 + threadIdx.x;
    if (i >= n8) return;
    float4 a = ((const float4*)src)[2 * i];
    float4 b = ((const float4*)src)[2 * i + 1];
    uint4 o;
    o.x = (unsigned int)f2bf(a.x) | ((unsigned int)f2bf(a.y) << 16);
    o.y = (unsigned int)f2bf(a.z) | ((unsigned int)f2bf(a.w) << 16);
    o.z = (unsigned int)f2bf(b.x) | ((unsigned int)f2bf(b.y) << 16);
    o.w = (unsigned int)f2bf(b.z) | ((unsigned int)f2bf(b.w) << 16);
    ((uint4*)dst)[i] = o;
}

// all 4 weight tensors in one launch (3 x 49152 + 393216 = 540672 uint4-units)
__global__ void pack_weights(const float* __restrict__ g1whh, const float* __restrict__ g1wih,
                             const float* __restrict__ g2whh, const float* __restrict__ g2wih,
                             unsigned short* __restrict__ wpk1, unsigned short* __restrict__ wih1,
                             unsigned short* __restrict__ wpk2, unsigned short* __restrict__ wih2) {
    int i = blockIdx.x * 256 + threadIdx.x;
    const float* src; unsigned short* dst; int j;
    if (i < 49152)       { src = g1whh; dst = wpk1; j = i; }
    else if (i < 98304)  { src = g1wih; dst = wih1; j = i - 49152; }
    else if (i < 147456) { src = g2whh; dst = wpk2; j = i - 98304; }
    else if (i < 540672) { src = g2wih; dst = wih2; j = i - 147456; }
    else return;
    float4 a = ((const float4*)src)[2 * j];
    float4 b = ((const float4*)src)[2 * j + 1];
    uint4 o;
    o.x = (unsigned int)f2bf(a.x) | ((unsigned int)f2bf(a.y) << 16);
    o.y = (unsigned int)f2bf(a.z) | ((unsigned int)f2bf(a.w) << 16);
    o.z = (unsigned int)f2bf(b.x) | ((unsigned int)f2bf(b.y) << 16);
    o.w = (unsigned int)f2bf(b.z) | ((unsigned int)f2bf(b.w) << 16);
    ((uint4*)dst)[j] = o;
}

// ---------------- MFMA GEMM, both GRU dirs fused; global_load_lds staging ----------------
// A bf16 [M][K], B bf16 [1536][K]. N=1536: dir0 cols 0..767 -> C0, dir1 -> C1 (row stride 768).
// LDS linear [128][32] (64B rows) for global_load_lds; 2-bit XOR chunk swizzle:
//   LDS[r][c] holds global chunk c^(r&3)  (source pre-swizzled; read addr swizzled; involution)
// -> 4-way max bank aliasing on ds_read_b128 instead of 8-way.
__global__ __launch_bounds__(256)
void gemm_2dir(const unsigned short* __restrict__ A, const unsigned short* __restrict__ B,
               const float* __restrict__ bias, unsigned short* __restrict__ C0,
               unsigned short* __restrict__ C1, int mbase, int K) {
    __shared__ __align__(16) unsigned short At[128][32];
    __shared__ __align__(16) unsigned short Bt[128][32];
    int tid = threadIdx.x;
    int m0 = blockIdx.x * 128, n0 = blockIdx.y * 128;
    int l = tid & 63, w = tid >> 6;          // 4 waves
    int wm = (w & 1) * 64, wn = (w >> 1) * 64;
    int lr = l & 15, kq = l >> 4;            // fragment row / k-quad
    // staging: wave w owns rows [w*32, w*32+32) of At and Bt; 2 calls of 16 rows each.
    // lane l -> subrow l>>2 (0..15), chunk-pos l&3; source chunk pre-swizzled by subrow&3.
    int subrow = l >> 2;
    int swc = (l & 3) ^ (subrow & 3);
    const unsigned short* gA0 = A + (size_t)(m0 + w * 32 + subrow) * K + swc * 8;
    const unsigned short* gA1 = A + (size_t)(m0 + w * 32 + 16 + subrow) * K + swc * 8;
    const unsigned short* gB0 = B + (size_t)(n0 + w * 32 + subrow) * K + swc * 8;
    const unsigned short* gB1 = B + (size_t)(n0 + w * 32 + 16 + subrow) * K + swc * 8;
    unsigned short* lA0 = &At[w * 32][0];
    unsigned short* lA1 = &At[w * 32 + 16][0];
    unsigned short* lB0 = &Bt[w * 32][0];
    unsigned short* lB1 = &Bt[w * 32 + 16][0];
    // read-side swizzled chunk (row&3 == lr&3 since tile row bases are mult of 16)
    int rchunk = (kq ^ (lr & 3)) * 8;
    floatx4 acc[4][4];
#pragma unroll
    for (int i = 0; i < 4; i++)
#pragma unroll
        for (int j = 0; j < 4; j++) acc[i][j] = (floatx4){0.f, 0.f, 0.f, 0.f};
    for (int k0 = 0; k0 < K; k0 += 32) {
        __syncthreads();                      // all reads of prev tile done
        gload_lds16(gA0 + k0, lA0);
        gload_lds16(gA1 + k0, lA1);
        gload_lds16(gB0 + k0, lB0);
        gload_lds16(gB1 + k0, lB1);
        __syncthreads();                      // drains vmcnt -> tile resident
        short8 af[4], bf[4];
#pragma unroll
        for (int i = 0; i < 4; i++) {
            af[i] = *(const short8*)&At[wm + i * 16 + lr][rchunk];
            bf[i] = *(const short8*)&Bt[wn + i * 16 + lr][rchunk];
        }
#pragma unroll
        for (int i = 0; i < 4; i++)
#pragma unroll
            for (int j = 0; j < 4; j++)
                acc[i][j] = __builtin_amdgcn_mfma_f32_16x16x32_bf16(af[i], bf[j], acc[i][j], 0, 0, 0);
    }
    int quad = l >> 4;
#pragma unroll
    for (int i = 0; i < 4; i++) {
#pragma unroll
        for (int j = 0; j < 4; j++) {
            int n = n0 + wn + j * 16 + lr;
            float bs = bias[n];
            unsigned short* dst = (n < 768) ? C0 : C1;
            int nn = (n < 768) ? n : n - 768;
#pragma unroll
            for (int r = 0; r < 4; r++) {
                int m = mbase + m0 + wm + i * 16 + quad * 4 + r;
                dst[(size_t)m * 768 + nn] = f2bf(acc[i][j][r] + bs);
            }
        }
    }
}

// ---------------- GRU scan: 1 stream/block, whh in VGPRs, in-wave gates ----------------
__global__ __launch_bounds__(512, 2)
void gru_scan_rreg(const unsigned short* __restrict__ gi_f,
                   const unsigned short* __restrict__ gi_b,
                   const unsigned short* __restrict__ whh_bf,
                   const float* __restrict__ bhh,
                   float* __restrict__ out) {
    int blk = blockIdx.x;
    int d = blk & 1, s = blk >> 1;
    const unsigned short* gi_blk = (d ? gi_b : gi_f) + (size_t)s * LSEQ * H3;
    const unsigned short* wb = whh_bf + (size_t)d * H3 * HID;

    __shared__ __align__(16) unsigned short h_pack[2][256];  // double-buffered h (bf16)

    int tid = threadIdx.x;
    int lane = tid & 63, wave = tid >> 6;
    int lr = lane & 15, kq = lane >> 4;

    short8 bq[6][8];
#pragma unroll
    for (int nt = 0; nt < 6; nt++) {
        int row = (nt >> 1) * 256 + wave * 32 + (nt & 1) * 16 + lr;
        const unsigned short* wp = wb + (size_t)row * HID + kq * 8;
#pragma unroll
        for (int kt = 0; kt < 8; kt++)
            bq[nt][kt] = *(const short8*)(wp + kt * 32);
    }

    int hh0 = wave * 32 + lr, hh1 = hh0 + 16;
    float br0 = bhh[d * H3 + hh0],       br1 = bhh[d * H3 + hh1];
    float bz0 = bhh[d * H3 + 256 + hh0], bz1 = bhh[d * H3 + 256 + hh1];
    float bn0 = bhh[d * H3 + 512 + hh0], bn1 = bhh[d * H3 + 512 + hh1];

    int t0 = d ? (LSEQ - 1) : 0;
    int tstep = d ? -1 : 1;

    if (tid < 128) ((unsigned int*)h_pack[0])[tid] = 0;
    float hold0 = 0.f, hold1 = 0.f;

    unsigned short gr0, gz0, gn0, gr1, gz1, gn1;
    {
        const unsigned short* gp = gi_blk + (size_t)t0 * H3;
        gr0 = gp[hh0]; gz0 = gp[256 + hh0]; gn0 = gp[512 + hh0];
        gr1 = gp[hh1]; gz1 = gp[256 + hh1]; gn1 = gp[512 + hh1];
    }
    __syncthreads();

    int cur = 0, t = t0;
    for (int step = 0; step < LSEQ; ++step) {
        unsigned short nr0 = 0, nz0 = 0, nn0 = 0, nr1 = 0, nz1 = 0, nn1 = 0;
        if (step + 1 < LSEQ) {
            const unsigned short* gp = gi_blk + (size_t)(t + tstep) * H3;
            nr0 = gp[hh0]; nz0 = gp[256 + hh0]; nn0 = gp[512 + hh0];
            nr1 = gp[hh1]; nz1 = gp[256 + hh1]; nn1 = gp[512 + hh1];
        }
        floatx4 acc[6];
#pragma unroll
        for (int nt = 0; nt < 6; nt++) acc[nt] = (floatx4){0.f, 0.f, 0.f, 0.f};
#pragma unroll
        for (int kt = 0; kt < 8; kt++) {
            short8 av = *(const short8*)&h_pack[cur][kt * 32 + kq * 8];  // broadcast
#pragma unroll
            for (int nt = 0; nt < 6; nt++)
                acc[nt] = __builtin_amdgcn_mfma_f32_16x16x32_bf16(av, bq[nt][kt], acc[nt], 0, 0, 0);
        }
        float rg0 = fsig(bf2f(gr0) + acc[0][0] + br0);
        float rg1 = fsig(bf2f(gr1) + acc[1][0] + br1);
        float zg0 = fsig(bf2f(gz0) + acc[2][0] + bz0);
        float zg1 = fsig(bf2f(gz1) + acc[3][0] + bz1);
        float ng0 = ftanh(bf2f(gn0) + rg0 * (acc[4][0] + bn0));
        float ng1 = ftanh(bf2f(gn1) + rg1 * (acc[5][0] + bn1));
        float h0 = (1.f - zg0) * ng0 + zg0 * hold0;
        float h1 = (1.f - zg1) * ng1 + zg1 * hold1;
        hold0 = h0; hold1 = h1;
        int nxt = cur ^ 1;
        if (kq == 0) {
            h_pack[nxt][hh0] = f2bf(h0);
            h_pack[nxt][hh1] = f2bf(h1);
            float* op = out + ((size_t)s * LSEQ + t) * H2 + d * HID;
            op[hh0] = h0;
            op[hh1] = h1;
        }
        gr0 = nr0; gz0 = nz0; gn0 = nn0;
        gr1 = nr1; gz1 = nz1; gn1 = nn1;
        __syncthreads();
        cur = nxt; t += tstep;
    }
}

// ---------------- bidaf helpers ----------------
__global__ void cwqw_kernel(const float* __restrict__ c, const float* __restrict__ q,
                            const float* __restrict__ w,
                            float* __restrict__ cw, float* __restrict__ qw) {
    int row = blockIdx.x;
    int lane = threadIdx.x;
    const float* src; const float* wv; float* dst; int r;
    if (row < 16384) { src = c; wv = w; dst = cw; r = row; }
    else { src = q; wv = w + 512; dst = qw; r = row - 16384; }
    const float* p = src + (size_t)r * H2;
    float acc = 0.f;
    for (int j = lane; j < H2; j += 64) acc += p[j] * wv[j];
    for (int off = 32; off; off >>= 1) acc += __shfl_down(acc, off);
    if (lane == 0) dst[r] = acc;
}

// smat via MFMA with split-bf16 (hi+lo) operands: fp32-quality scores.
// S[m][n] = sum_k (c[m][k]*w2[k]) * q[n][k]  + cw[m] + qw[n] + bsum
__global__ __launch_bounds__(256)
void smat_mfma(const float* __restrict__ c, const float* __restrict__ q,
               const float* __restrict__ w2, const float* __restrict__ bvec,
               const float* __restrict__ cw, const float* __restrict__ qw,
               float* __restrict__ smat) {
    __shared__ __align__(16) unsigned short Ah[128][40];
    __shared__ __align__(16) unsigned short Al[128][40];
    __shared__ __align__(16) unsigned short Bh[128][40];
    __shared__ __align__(16) unsigned short Bl[128][40];
    int b = blockIdx.z;
    int m0 = blockIdx.x * 128, n0 = blockIdx.y * 128;
    int tid = threadIdx.x;
    int l = tid & 63, w = tid >> 6;
    int wm = (w & 1) * 64, wn = (w >> 1) * 64;
    int lr = l & 15, koff = (l >> 4) * 8;
    int srow = tid >> 1, scol = (tid & 1) * 16;
    floatx4 acc[4][4];
#pragma unroll
    for (int i = 0; i < 4; i++)
#pragma unroll
        for (int j = 0; j < 4; j++) acc[i][j] = (floatx4){0.f, 0.f, 0.f, 0.f};
    const float* ap0 = c + (size_t)(b * 256 + m0 + srow) * H2 + scol;
    const float* bp0 = q + (size_t)(b * 256 + n0 + srow) * H2 + scol;
    for (int k0 = 0; k0 < H2; k0 += 32) {
        float av[16], bv[16], wv[16];
        *(float4*)&av[0]  = *(const float4*)(ap0 + k0);
        *(float4*)&av[4]  = *(const float4*)(ap0 + k0 + 4);
        *(float4*)&av[8]  = *(const float4*)(ap0 + k0 + 8);
        *(float4*)&av[12] = *(const float4*)(ap0 + k0 + 12);
        *(float4*)&bv[0]  = *(const float4*)(bp0 + k0);
        *(float4*)&bv[4]  = *(const float4*)(bp0 + k0 + 4);
        *(float4*)&bv[8]  = *(const float4*)(bp0 + k0 + 8);
        *(float4*)&bv[12] = *(const float4*)(bp0 + k0 + 12);
        *(float4*)&wv[0]  = *(const float4*)(w2 + k0 + scol);
        *(float4*)&wv[4]  = *(const float4*)(w2 + k0 + scol + 4);
        *(float4*)&wv[8]  = *(const float4*)(w2 + k0 + scol + 8);
        *(float4*)&wv[12] = *(const float4*)(w2 + k0 + scol + 12);
        unsigned int ahw[8], alw[8], bhw[8], blw[8];
#pragma unroll
        for (int j = 0; j < 8; j++) {
            float p0 = av[2 * j] * wv[2 * j], p1 = av[2 * j + 1] * wv[2 * j + 1];
            unsigned short h0, s0, h1, s1;
            bfsplit(p0, h0, s0); bfsplit(p1, h1, s1);
            ahw[j] = (unsigned int)h0 | ((unsigned int)h1 << 16);
            alw[j] = (unsigned int)s0 | ((unsigned int)s1 << 16);
            unsigned short g0, t0, g1, t1;
            bfsplit(bv[2 * j], g0, t0); bfsplit(bv[2 * j + 1], g1, t1);
            bhw[j] = (unsigned int)g0 | ((unsigned int)g1 << 16);
            blw[j] = (unsigned int)t0 | ((unsigned int)t1 << 16);
        }
        __syncthreads();
        *(uint4*)&Ah[srow][scol]     = *(uint4*)&ahw[0];
        *(uint4*)&Ah[srow][scol + 8] = *(uint4*)&ahw[4];
        *(uint4*)&Al[srow][scol]     = *(uint4*)&alw[0];
        *(uint4*)&Al[srow][scol + 8] = *(uint4*)&alw[4];
        *(uint4*)&Bh[srow][scol]     = *(uint4*)&bhw[0];
        *(uint4*)&Bh[srow][scol + 8] = *(uint4*)&bhw[4];
        *(uint4*)&Bl[srow][scol]     = *(uint4*)&blw[0];
        *(uint4*)&Bl[srow][scol + 8] = *(uint4*)&blw[4];
        __syncthreads();
        short8 afh[4], afl[4], bfh[4], bfl[4];
#pragma unroll
        for (int i = 0; i < 4; i++) {
            afh[i] = *(const short8*)&Ah[wm + i * 16 + lr][koff];
            afl[i] = *(const short8*)&Al[wm + i * 16 + lr][koff];
            bfh[i] = *(const short8*)&Bh[wn + i * 16 + lr][koff];
            bfl[i] = *(const short8*)&Bl[wn + i * 16 + lr][koff];
        }
#pragma unroll
        for (int i = 0; i < 4; i++)
#pragma unroll
            for (int j = 0; j < 4; j++) {
                acc[i][j] = __builtin_amdgcn_mfma_f32_16x16x32_bf16(afl[i], bfh[j], acc[i][j], 0, 0, 0);
                acc[i][j] = __builtin_amdgcn_mfma_f32_16x16x32_bf16(afh[i], bfl[j], acc[i][j], 0, 0, 0);
                acc[i][j] = __builtin_amdgcn_mfma_f32_16x16x32_bf16(afh[i], bfh[j], acc[i][j], 0, 0, 0);
            }
    }
    float bsum = bvec[0] + bvec[1] + bvec[2];
    int quad = l >> 4;
#pragma unroll
    for (int i = 0; i < 4; i++) {
#pragma unroll
        for (int j = 0; j < 4; j++) {
            int n = n0 + wn + j * 16 + lr;
            float qwv = qw[b * 256 + n] + bsum;
#pragma unroll
            for (int r = 0; r < 4; r++) {
                int m = m0 + wm + i * 16 + quad * 4 + r;
                smat[((size_t)(b * 256 + m)) * 256 + n] = acc[i][j][r] + cw[b * 256 + m] + qwv;
            }
        }
    }
}

__global__ void softmax_kernel(float* __restrict__ smat, float* __restrict__ rowmax) {
    int row = blockIdx.x;
    int lane = threadIdx.x;
    float* p = smat + (size_t)row * LSEQ;
    float v[4];
    float mx = -1e30f;
#pragma unroll
    for (int j = 0; j < 4; j++) { v[j] = p[lane + j * 64]; mx = fmaxf(mx, v[j]); }
    for (int off = 32; off; off >>= 1) mx = fmaxf(mx, __shfl_down(mx, off));
    mx = __shfl(mx, 0);
    float sum = 0.f;
#pragma unroll
    for (int j = 0; j < 4; j++) { v[j] = __expf(v[j] - mx); sum += v[j]; }
    for (int off = 32; off; off >>= 1) sum += __shfl_down(sum, off);
    sum = __shfl(sum, 0);
    float inv = 1.f / sum;
#pragma unroll
    for (int j = 0; j < 4; j++) p[lane + j * 64] = v[j] * inv;
    if (lane == 0) rowmax[row] = mx;
}

__global__ void bb_kernel(const float* __restrict__ rowmax, float* __restrict__ bb) {
    int b = blockIdx.x; int t = threadIdx.x;
    __shared__ float red[256];
    float v = rowmax[b * LSEQ + t];
    red[t] = v; __syncthreads();
    for (int s = 128; s; s >>= 1) { if (t < s) red[t] = fmaxf(red[t], red[t + s]); __syncthreads(); }
    float mx = red[0]; __syncthreads();
    float e = __expf(v - mx);
    red[t] = e; __syncthreads();
    for (int s = 128; s; s >>= 1) { if (t < s) red[t] += red[t + s]; __syncthreads(); }
    bb[b * LSEQ + t] = e / red[0];
}

// q2c: grid (64,4) x 128 thr; 4 independent accumulators break the add chain
__global__ void q2c_kernel(const float* __restrict__ bb, const float* __restrict__ c,
                           float* __restrict__ q2c) {
    int b = blockIdx.x;
    int d = blockIdx.y * 128 + threadIdx.x;
    const float* cb = c + (size_t)b * LSEQ * H2 + d;
    const float* bbp = bb + b * LSEQ;
    float a0 = 0.f, a1 = 0.f, a2 = 0.f, a3 = 0.f;
    for (int i = 0; i < LSEQ; i += 4) {
        a0 += bbp[i]     * cb[(size_t)i * H2];
        a1 += bbp[i + 1] * cb[(size_t)(i + 1) * H2];
        a2 += bbp[i + 2] * cb[(size_t)(i + 2) * H2];
        a3 += bbp[i + 3] * cb[(size_t)(i + 3) * H2];
    }
    q2c[b * H2 + d] = (a0 + a1) + (a2 + a3);
}

// c2q via MFMA split-bf16 with FUSED fixup03 epilogue.
// C2Q[m][n] = sum_k amat[m][k] * q[k][n]; writes all four ATT quadrants for n in [0,512):
//   att[row][n]      = relu(c[row][n])
//   att[row][512+n]  = relu(c2q)
//   att[row][1024+n] = relu(c[row][n] * c2q)
//   att[row][1536+n] = relu(c[row][n] * q2c[b][n])
__global__ __launch_bounds__(256)
void c2q_fix_mfma(const float* __restrict__ amat, const float* __restrict__ q,
                  const float* __restrict__ c, const float* __restrict__ q2c,
                  float* __restrict__ att, int add) {
    __shared__ __align__(16) unsigned short Ah[128][40];
    __shared__ __align__(16) unsigned short Al[128][40];
    __shared__ __align__(16) unsigned short Bh[128][40];
    __shared__ __align__(16) unsigned short Bl[128][40];
    int b = blockIdx.z;
    int m0 = blockIdx.x * 128, n0 = blockIdx.y * 128;
    int tid = threadIdx.x;
    int l = tid & 63, w = tid >> 6;
    int wm = (w & 1) * 64, wn = (w >> 1) * 64;
    int lr = l & 15, koff = (l >> 4) * 8;
    int srow = tid >> 1, scol = (tid & 1) * 16;
    int bn = tid & 127, bkh = tid >> 7;           // B-stage: column n0+bn, k-half bkh
    floatx4 acc[4][4];
#pragma unroll
    for (int i = 0; i < 4; i++)
#pragma unroll
        for (int j = 0; j < 4; j++) acc[i][j] = (floatx4){0.f, 0.f, 0.f, 0.f};
    for (int k0 = 0; k0 < LSEQ; k0 += 32) {
        float av[16];
        const float* ap = amat + (size_t)(b * 256 + m0 + srow) * 256 + k0 + scol;
        *(float4*)&av[0]  = *(const float4*)(ap);
        *(float4*)&av[4]  = *(const float4*)(ap + 4);
        *(float4*)&av[8]  = *(const float4*)(ap + 8);
        *(float4*)&av[12] = *(const float4*)(ap + 12);
        float qv[16];
        const float* qp = q + (size_t)(b * 256 + k0 + bkh * 16) * H2 + n0 + bn;
#pragma unroll
        for (int j = 0; j < 16; j++) qv[j] = qp[(size_t)j * H2];
        unsigned int ahw[8], alw[8], bhw[8], blw[8];
#pragma unroll
        for (int j = 0; j < 8; j++) {
            unsigned short h0, s0, h1, s1;
            bfsplit(av[2 * j], h0, s0); bfsplit(av[2 * j + 1], h1, s1);
            ahw[j] = (unsigned int)h0 | ((unsigned int)h1 << 16);
            alw[j] = (unsigned int)s0 | ((unsigned int)s1 << 16);
            unsigned short g0, t0, g1, t1;
            bfsplit(qv[2 * j], g0, t0); bfsplit(qv[2 * j + 1], g1, t1);
            bhw[j] = (unsigned int)g0 | ((unsigned int)g1 << 16);
            blw[j] = (unsigned int)t0 | ((unsigned int)t1 << 16);
        }
        __syncthreads();
        *(uint4*)&Ah[srow][scol]         = *(uint4*)&ahw[0];
        *(uint4*)&Ah[srow][scol + 8]     = *(uint4*)&ahw[4];
        *(uint4*)&Al[srow][scol]         = *(uint4*)&alw[0];
        *(uint4*)&Al[srow][scol + 8]     = *(uint4*)&alw[4];
        *(uint4*)&Bh[bn][bkh * 16]       = *(uint4*)&bhw[0];
        *(uint4*)&Bh[bn][bkh * 16 + 8]   = *(uint4*)&bhw[4];
        *(uint4*)&Bl[bn][bkh * 16]       = *(uint4*)&blw[0];
        *(uint4*)&Bl[bn][bkh * 16 + 8]   = *(uint4*)&blw[4];
        __syncthreads();
        short8 afh[4], afl[4], bfh[4], bfl[4];
#pragma unroll
        for (int i = 0; i < 4; i++) {
            afh[i] = *(const short8*)&Ah[wm + i * 16 + lr][koff];
            afl[i] = *(const short8*)&Al[wm + i * 16 + lr][koff];
            bfh[i] = *(const short8*)&Bh[wn + i * 16 + lr][koff];
            bfl[i] = *(const short8*)&Bl[wn + i * 16 + lr][koff];
        }
#pragma unroll
        for (int i = 0; i < 4; i++)
#pragma unroll
            for (int j = 0; j < 4; j++) {
                acc[i][j] = __builtin_amdgcn_mfma_f32_16x16x32_bf16(afl[i], bfh[j], acc[i][j], 0, 0, 0);
                acc[i][j] = __builtin_amdgcn_mfma_f32_16x16x32_bf16(afh[i], bfl[j], acc[i][j], 0, 0, 0);
                acc[i][j] = __builtin_amdgcn_mfma_f32_16x16x32_bf16(afh[i], bfh[j], acc[i][j], 0, 0, 0);
            }
    }
    int quad = l >> 4;
#pragma unroll
    for (int i = 0; i < 4; i++) {
#pragma unroll
        for (int j = 0; j < 4; j++) {
            int n = n0 + wn + j * 16 + lr;
            float q2cv = q2c[b * H2 + n];
#pragma unroll
            for (int r = 0; r < 4; r++) {
                int m = m0 + wm + i * 16 + quad * 4 + r;
                size_t row = (size_t)b * 256 + m;
                float a = acc[i][j][r];
                float cv = c[row * H2 + n];
                float v0 = fmaxf(cv, 0.f);
                float v1 = fmaxf(a, 0.f);
                float v2 = fmaxf(cv * a, 0.f);
                float v3 = fmaxf(cv * q2cv, 0.f);
                float* p0 = att + row * H8 + n;
                float* p1 = p0 + 512;
                float* p2 = p0 + 1024;
                float* p3 = p0 + 1536;
                if (add) { *p0 += v0; *p1 += v1; *p2 += v2; *p3 += v3; }
                else     { *p0 = v0;  *p1 = v1;  *p2 = v2;  *p3 = v3; }
            }
        }
    }
}

// ---------------- final rank reduce ----------------
__global__ void reduce1_kernel(const float* __restrict__ s, const float* __restrict__ rw,
                               float* __restrict__ part) {
    int bo = blockIdx.x;
    int p = blockIdx.y;
    int t = threadIdx.x;
    const float* s0 = s + (size_t)(2 * bo) * 524288;
    const float* s1 = s0 + 524288;
    size_t base = (size_t)p * 65536;
    float acc = 0.f;
    for (int j = t; j < 65536; j += 256) {
        size_t m = base + j;
        acc += rw[m] * fmaxf(s0[m], s1[m]);
    }
    __shared__ float red[256];
    red[t] = acc; __syncthreads();
    for (int ss = 128; ss; ss >>= 1) { if (t < ss) red[t] += red[t + ss]; __syncthreads(); }
    if (t == 0) part[bo * 8 + p] = red[0];
}

__global__ void reduce2_kernel(const float* __restrict__ part, const float* __restrict__ rb,
                               float* __restrict__ out) {
    int t = threadIdx.x;
    float a = rb[0];
    for (int p = 0; p < 8; p++) a += part[t * 8 + p];
    out[t] = a;
}

extern "C" void kernel_launch(void* const* d_in, const int* in_sizes, int n_in,
                              void* d_out, int out_size, void* d_ws, size_t ws_size,
                              hipStream_t stream) {
    const int* question = (const int*)d_in[0];
    const int* article  = (const int*)d_in[1];
    const float* emb    = (const float*)d_in[2];
    const float* g1_wih = (const float*)d_in[3];
    const float* g1_whh = (const float*)d_in[4];
    const float* g1_bih = (const float*)d_in[5];
    const float* g1_bhh = (const float*)d_in[6];
    const float* g2_wih = (const float*)d_in[7];
    const float* g2_whh = (const float*)d_in[8];
    const float* g2_bih = (const float*)d_in[9];
    const float* g2_bhh = (const float*)d_in[10];
    const float* b1_w   = (const float*)d_in[11];
    const float* b1_b   = (const float*)d_in[12];
    const float* b2_w   = (const float*)d_in[13];
    const float* b2_b   = (const float*)d_in[14];
    const float* rank_w = (const float*)d_in[15];
    const float* rank_b = (const float*)d_in[16];
    float* ws = (float*)d_ws;
    float* out = (float*)d_out;

    // ---- workspace layout (float offsets; phase-liveness verified) ----
    // weights  [0, 2162688)
    // smallbuf [2162688, 2293760)
    // slot A   [2293760, 6488064):  XEMBB (P1-2) / SMAT (P4,P7)
    // slot A'  [2293760, 14876672): GI2B (P5-6)
    // HBUF     [6488064, 23265280): scan1 out (P3-4); head QH, tail AH
    // ATTBH    [14876672, 23265280): half-M bf16 ATT mirror (P5 only, 8.39M fl OK)
    // AX2      [14876672, 23265280): scan2 out (P6-7)
    // ATT      [25165824, 58720256): P4 -> end; GI1B (P2-3) aliases its head
    unsigned short* WPK1  = (unsigned short*)(ws);
    unsigned short* WIH1B = (unsigned short*)(ws + 196608);
    unsigned short* WPK2  = (unsigned short*)(ws + 393216);
    unsigned short* WIH2B = (unsigned short*)(ws + 589824);
    float* CW   = ws + 2162688;
    float* QW   = ws + 2179072;
    float* RM   = ws + 2195456;
    float* BBv  = ws + 2211840;
    float* Q2C  = ws + 2228224;
    float* PART = ws + 2260992;
    unsigned short* XEMBB = (unsigned short*)(ws + 2293760);
    float*          SMAT  = ws + 2293760;
    unsigned short* GI2B  = (unsigned short*)(ws + 2293760);
    float*          HBUF  = ws + 6488064;
    unsigned short* ATTBH = (unsigned short*)(ws + 14876672);
    float*          AX2   = ws + 14876672;
    float*          ATT   = ws + 25165824;
    unsigned short* GI1B  = (unsigned short*)(ws + 25165824);

    // 1. embed (bf16) + pack all weights to bf16 (single launch)
    embed_kernel<<<32768, 256, 0, stream>>>(question, article, emb, XEMBB);
    pack_weights<<<2112, 256, 0, stream>>>(g1_whh, g1_wih, g2_whh, g2_wih,
                                           WPK1, WIH1B, WPK2, WIH2B);

    // 2. GRU1 input gates, both dirs fused: M=32768 N=1536 K=256
    gemm_2dir<<<dim3(256, 12), 256, 0, stream>>>(
        XEMBB, WIH1B, g1_bih, GI1B, GI1B + (size_t)25165824, 0, 256);
    // 3. GRU1 scan
    gru_scan_rreg<<<256, 512, 0, stream>>>(GI1B, GI1B + (size_t)25165824, WPK1, g1_bhh, HBUF);

    float* QH = HBUF;
    float* AH = HBUF + (size_t)64 * 256 * 512;

    // 4. BiDAF1: c=QH, q=AH -> ATT (set); fixup03 fused into c2q
    {
        cwqw_kernel<<<32768, 64, 0, stream>>>(QH, AH, b1_w, CW, QW);
        smat_mfma<<<dim3(2, 2, 64), 256, 0, stream>>>(QH, AH, b1_w + 1024, b1_b, CW, QW, SMAT);
        softmax_kernel<<<16384, 64, 0, stream>>>(SMAT, RM);
        bb_kernel<<<64, 256, 0, stream>>>(RM, BBv);
        q2c_kernel<<<dim3(64, 4), 128, 0, stream>>>(BBv, QH, Q2C);
        c2q_fix_mfma<<<dim3(2, 4, 64), 256, 0, stream>>>(SMAT, AH, QH, Q2C, ATT, 0);
    }

    // 5. GRU2 input gates: half-M buffered ATT->bf16 pack + fused-dir all-bf16 GEMM
    for (int half = 0; half < 2; half++) {
        pack_bf8<<<8192, 256, 0, stream>>>(ATT + (size_t)half * 16777216, ATTBH, 2097152);
        gemm_2dir<<<dim3(64, 12), 256, 0, stream>>>(
            ATTBH, WIH2B, g2_bih, GI2B, GI2B + (size_t)12582912, half * 8192, 2048);
    }
    // 6. GRU2 scan (AX2 overwrites dead ATTBH)
    gru_scan_rreg<<<128, 512, 0, stream>>>(GI2B, GI2B + (size_t)12582912, WPK2, g2_bhh, AX2);

    // 7. BiDAF2: c=q=AX2 -> ATT (accumulate); fixup03 fused into c2q
    {
        cwqw_kernel<<<32768, 64, 0, stream>>>(AX2, AX2, b2_w, CW, QW);
        smat_mfma<<<dim3(2, 2, 64), 256, 0, stream>>>(AX2, AX2, b2_w + 1024, b2_b, CW, QW, SMAT);
        softmax_kernel<<<16384, 64, 0, stream>>>(SMAT, RM);
        bb_kernel<<<64, 256, 0, stream>>>(RM, BBv);
        q2c_kernel<<<dim3(64, 4), 128, 0, stream>>>(BBv, AX2, Q2C);
        c2q_fix_mfma<<<dim3(2, 4, 64), 256, 0, stream>>>(SMAT, AX2, AX2, Q2C, ATT, 1);
    }

    // 8. rank reduce
    reduce1_kernel<<<dim3(32, 8), 256, 0, stream>>>(ATT, rank_w, PART);
    reduce2_kernel<<<1, 32, 0, stream>>>(PART, rank_b, out);
}

// Round 10
// 1179.922 us; speedup vs baseline: 1.4343x; 1.1204x over previous
//
#include <hip/hip_runtime.h>
#include <math.h>

#define LSEQ 256
#define HID 256
#define H2 512
#define H3 768
#define H8 2048

typedef __attribute__((ext_vector_type(8))) short short8;
typedef __attribute__((ext_vector_type(4))) float floatx4;

__device__ __forceinline__ unsigned short f2bf(float f) {
    unsigned int u = __float_as_uint(f);
    u = (u + 0x7FFFu + ((u >> 16) & 1u)) >> 16;
    return (unsigned short)u;
}
__device__ __forceinline__ float bf2f(unsigned short h) {
    return __uint_as_float(((unsigned int)h) << 16);
}
__device__ __forceinline__ float fsig(float x) {
    return __builtin_amdgcn_rcpf(1.f + __expf(-x));
}
__device__ __forceinline__ float ftanh(float x) {
    return __builtin_fmaf(2.f, __builtin_amdgcn_rcpf(1.f + __expf(-2.f * x)), -1.f);
}
// split fp32 -> (hi,lo) bf16 pair; hi+lo reproduces x to ~2^-17 rel
__device__ __forceinline__ void bfsplit(float x, unsigned short& hi, unsigned short& lo) {
    hi = f2bf(x);
    lo = f2bf(x - bf2f(hi));
}
// async global->LDS 16B per lane: LDS dest = base + lane*16 (wave-uniform base)
__device__ __forceinline__ void gload_lds16(const void* g, void* l) {
    __builtin_amdgcn_global_load_lds(
        (const __attribute__((address_space(1))) unsigned int*)g,
        (__attribute__((address_space(3))) unsigned int*)l, 16, 0, 0);
}

// ---------------- embed (bf16 out) ----------------
__global__ void embed_kernel(const int* __restrict__ question,
                             const int* __restrict__ article,
                             const float* __restrict__ emb,
                             unsigned short* __restrict__ xemb) {
    int gid = blockIdx.x * 256 + threadIdx.x;   // 128*256*256
    int d = gid & 255;
    int rl = gid >> 8;
    int l = rl & 255;
    int stream = rl >> 8;
    int id;
    if (stream < 64) {
        int b = stream >> 3, o = (stream & 7) >> 1;
        id = question[(b * 4 + o) * 256 + l];
    } else {
        id = article[(stream - 64) * 256 + l];
    }
    xemb[(size_t)gid] = f2bf(emb[(size_t)id * 256 + d]);
}

// all 4 weight tensors in one launch (3 x 49152 + 393216 = 540672 uint4-units)
__global__ void pack_weights(const float* __restrict__ g1whh, const float* __restrict__ g1wih,
                             const float* __restrict__ g2whh, const float* __restrict__ g2wih,
                             unsigned short* __restrict__ wpk1, unsigned short* __restrict__ wih1,
                             unsigned short* __restrict__ wpk2, unsigned short* __restrict__ wih2) {
    int i = blockIdx.x * 256 + threadIdx.x;
    const float* src; unsigned short* dst; int j;
    if (i < 49152)       { src = g1whh; dst = wpk1; j = i; }
    else if (i < 98304)  { src = g1wih; dst = wih1; j = i - 49152; }
    else if (i < 147456) { src = g2whh; dst = wpk2; j = i - 98304; }
    else if (i < 540672) { src = g2wih; dst = wih2; j = i - 147456; }
    else return;
    float4 a = ((const float4*)src)[2 * j];
    float4 b = ((const float4*)src)[2 * j + 1];
    uint4 o;
    o.x = (unsigned int)f2bf(a.x) | ((unsigned int)f2bf(a.y) << 16);
    o.y = (unsigned int)f2bf(a.z) | ((unsigned int)f2bf(a.w) << 16);
    o.z = (unsigned int)f2bf(b.x) | ((unsigned int)f2bf(b.y) << 16);
    o.w = (unsigned int)f2bf(b.z) | ((unsigned int)f2bf(b.w) << 16);
    ((uint4*)dst)[j] = o;
}

// ---------------- MFMA GEMM, both GRU dirs fused; global_load_lds staging ----------------
// A bf16 [M][K], B bf16 [1536][K]. N=1536: dir0 cols 0..767 -> C0, dir1 -> C1 (row stride 768).
// LDS linear [128][32] for global_load_lds; 2-bit XOR chunk swizzle (source pre-swizzled,
// read addr swizzled; involution) -> 4-way max bank aliasing on ds_read_b128.
__global__ __launch_bounds__(256)
void gemm_2dir(const unsigned short* __restrict__ A, const unsigned short* __restrict__ B,
               const float* __restrict__ bias, unsigned short* __restrict__ C0,
               unsigned short* __restrict__ C1, int mbase, int K) {
    __shared__ __align__(16) unsigned short At[128][32];
    __shared__ __align__(16) unsigned short Bt[128][32];
    int tid = threadIdx.x;
    int m0 = blockIdx.x * 128, n0 = blockIdx.y * 128;
    int l = tid & 63, w = tid >> 6;          // 4 waves
    int wm = (w & 1) * 64, wn = (w >> 1) * 64;
    int lr = l & 15, kq = l >> 4;
    int subrow = l >> 2;
    int swc = (l & 3) ^ (subrow & 3);
    const unsigned short* gA0 = A + (size_t)(m0 + w * 32 + subrow) * K + swc * 8;
    const unsigned short* gA1 = A + (size_t)(m0 + w * 32 + 16 + subrow) * K + swc * 8;
    const unsigned short* gB0 = B + (size_t)(n0 + w * 32 + subrow) * K + swc * 8;
    const unsigned short* gB1 = B + (size_t)(n0 + w * 32 + 16 + subrow) * K + swc * 8;
    unsigned short* lA0 = &At[w * 32][0];
    unsigned short* lA1 = &At[w * 32 + 16][0];
    unsigned short* lB0 = &Bt[w * 32][0];
    unsigned short* lB1 = &Bt[w * 32 + 16][0];
    int rchunk = (kq ^ (lr & 3)) * 8;
    floatx4 acc[4][4];
#pragma unroll
    for (int i = 0; i < 4; i++)
#pragma unroll
        for (int j = 0; j < 4; j++) acc[i][j] = (floatx4){0.f, 0.f, 0.f, 0.f};
    for (int k0 = 0; k0 < K; k0 += 32) {
        __syncthreads();
        gload_lds16(gA0 + k0, lA0);
        gload_lds16(gA1 + k0, lA1);
        gload_lds16(gB0 + k0, lB0);
        gload_lds16(gB1 + k0, lB1);
        __syncthreads();
        short8 af[4], bf[4];
#pragma unroll
        for (int i = 0; i < 4; i++) {
            af[i] = *(const short8*)&At[wm + i * 16 + lr][rchunk];
            bf[i] = *(const short8*)&Bt[wn + i * 16 + lr][rchunk];
        }
#pragma unroll
        for (int i = 0; i < 4; i++)
#pragma unroll
            for (int j = 0; j < 4; j++)
                acc[i][j] = __builtin_amdgcn_mfma_f32_16x16x32_bf16(af[i], bf[j], acc[i][j], 0, 0, 0);
    }
    int quad = l >> 4;
#pragma unroll
    for (int i = 0; i < 4; i++) {
#pragma unroll
        for (int j = 0; j < 4; j++) {
            int n = n0 + wn + j * 16 + lr;
            float bs = bias[n];
            unsigned short* dst = (n < 768) ? C0 : C1;
            int nn = (n < 768) ? n : n - 768;
#pragma unroll
            for (int r = 0; r < 4; r++) {
                int m = mbase + m0 + wm + i * 16 + quad * 4 + r;
                dst[(size_t)m * 768 + nn] = f2bf(acc[i][j][r] + bs);
            }
        }
    }
}

// ---------------- GRU scan: 1 stream/block, whh in VGPRs, in-wave gates ----------------
__global__ __launch_bounds__(512, 2)
void gru_scan_rreg(const unsigned short* __restrict__ gi_f,
                   const unsigned short* __restrict__ gi_b,
                   const unsigned short* __restrict__ whh_bf,
                   const float* __restrict__ bhh,
                   float* __restrict__ out) {
    int blk = blockIdx.x;
    int d = blk & 1, s = blk >> 1;
    const unsigned short* gi_blk = (d ? gi_b : gi_f) + (size_t)s * LSEQ * H3;
    const unsigned short* wb = whh_bf + (size_t)d * H3 * HID;

    __shared__ __align__(16) unsigned short h_pack[2][256];  // double-buffered h (bf16)

    int tid = threadIdx.x;
    int lane = tid & 63, wave = tid >> 6;
    int lr = lane & 15, kq = lane >> 4;

    short8 bq[6][8];
#pragma unroll
    for (int nt = 0; nt < 6; nt++) {
        int row = (nt >> 1) * 256 + wave * 32 + (nt & 1) * 16 + lr;
        const unsigned short* wp = wb + (size_t)row * HID + kq * 8;
#pragma unroll
        for (int kt = 0; kt < 8; kt++)
            bq[nt][kt] = *(const short8*)(wp + kt * 32);
    }

    int hh0 = wave * 32 + lr, hh1 = hh0 + 16;
    float br0 = bhh[d * H3 + hh0],       br1 = bhh[d * H3 + hh1];
    float bz0 = bhh[d * H3 + 256 + hh0], bz1 = bhh[d * H3 + 256 + hh1];
    float bn0 = bhh[d * H3 + 512 + hh0], bn1 = bhh[d * H3 + 512 + hh1];

    int t0 = d ? (LSEQ - 1) : 0;
    int tstep = d ? -1 : 1;

    if (tid < 128) ((unsigned int*)h_pack[0])[tid] = 0;
    float hold0 = 0.f, hold1 = 0.f;

    unsigned short gr0, gz0, gn0, gr1, gz1, gn1;
    {
        const unsigned short* gp = gi_blk + (size_t)t0 * H3;
        gr0 = gp[hh0]; gz0 = gp[256 + hh0]; gn0 = gp[512 + hh0];
        gr1 = gp[hh1]; gz1 = gp[256 + hh1]; gn1 = gp[512 + hh1];
    }
    __syncthreads();

    int cur = 0, t = t0;
    for (int step = 0; step < LSEQ; ++step) {
        unsigned short nr0 = 0, nz0 = 0, nn0 = 0, nr1 = 0, nz1 = 0, nn1 = 0;
        if (step + 1 < LSEQ) {
            const unsigned short* gp = gi_blk + (size_t)(t + tstep) * H3;
            nr0 = gp[hh0]; nz0 = gp[256 + hh0]; nn0 = gp[512 + hh0];
            nr1 = gp[hh1]; nz1 = gp[256 + hh1]; nn1 = gp[512 + hh1];
        }
        floatx4 acc[6];
#pragma unroll
        for (int nt = 0; nt < 6; nt++) acc[nt] = (floatx4){0.f, 0.f, 0.f, 0.f};
#pragma unroll
        for (int kt = 0; kt < 8; kt++) {
            short8 av = *(const short8*)&h_pack[cur][kt * 32 + kq * 8];  // broadcast
#pragma unroll
            for (int nt = 0; nt < 6; nt++)
                acc[nt] = __builtin_amdgcn_mfma_f32_16x16x32_bf16(av, bq[nt][kt], acc[nt], 0, 0, 0);
        }
        float rg0 = fsig(bf2f(gr0) + acc[0][0] + br0);
        float rg1 = fsig(bf2f(gr1) + acc[1][0] + br1);
        float zg0 = fsig(bf2f(gz0) + acc[2][0] + bz0);
        float zg1 = fsig(bf2f(gz1) + acc[3][0] + bz1);
        float ng0 = ftanh(bf2f(gn0) + rg0 * (acc[4][0] + bn0));
        float ng1 = ftanh(bf2f(gn1) + rg1 * (acc[5][0] + bn1));
        float h0 = (1.f - zg0) * ng0 + zg0 * hold0;
        float h1 = (1.f - zg1) * ng1 + zg1 * hold1;
        hold0 = h0; hold1 = h1;
        int nxt = cur ^ 1;
        if (kq == 0) {
            h_pack[nxt][hh0] = f2bf(h0);
            h_pack[nxt][hh1] = f2bf(h1);
            float* op = out + ((size_t)s * LSEQ + t) * H2 + d * HID;
            op[hh0] = h0;
            op[hh1] = h1;
        }
        gr0 = nr0; gz0 = nz0; gn0 = nn0;
        gr1 = nr1; gz1 = nz1; gn1 = nn1;
        __syncthreads();
        cur = nxt; t += tstep;
    }
}

// ---------------- smat via MFMA split-bf16, with FUSED cw/qw row/col dots ----------------
// S[m][n] = sum_k (c[m][k]*w2[k]) * q[n][k] + cw[m] + qw[n] + bsum
// cw[m] = dot(c[m], w1[0:512]); qw[n] = dot(q[n], w1[512:1024]); w2 = w1 + 1024.
__global__ __launch_bounds__(256)
void smat_mfma(const float* __restrict__ c, const float* __restrict__ q,
               const float* __restrict__ w1, const float* __restrict__ bvec,
               float* __restrict__ smat) {
    __shared__ __align__(16) unsigned short Ah[128][40];
    __shared__ __align__(16) unsigned short Al[128][40];
    __shared__ __align__(16) unsigned short Bh[128][40];
    __shared__ __align__(16) unsigned short Bl[128][40];
    __shared__ float cwl[128];
    __shared__ float qwl[128];
    const float* w2 = w1 + 1024;
    int b = blockIdx.z;
    int m0 = blockIdx.x * 128, n0 = blockIdx.y * 128;
    int tid = threadIdx.x;
    int l = tid & 63, w = tid >> 6;
    int wm = (w & 1) * 64, wn = (w >> 1) * 64;
    int lr = l & 15, koff = (l >> 4) * 8;
    int srow = tid >> 1, scol = (tid & 1) * 16;
    floatx4 acc[4][4];
#pragma unroll
    for (int i = 0; i < 4; i++)
#pragma unroll
        for (int j = 0; j < 4; j++) acc[i][j] = (floatx4){0.f, 0.f, 0.f, 0.f};
    const float* ap0 = c + (size_t)(b * 256 + m0 + srow) * H2 + scol;
    const float* bp0 = q + (size_t)(b * 256 + n0 + srow) * H2 + scol;
    float pcw = 0.f, pqw = 0.f;
    for (int k0 = 0; k0 < H2; k0 += 32) {
        float av[16], bv[16], wv[16], wc[16], wq[16];
        *(float4*)&av[0]  = *(const float4*)(ap0 + k0);
        *(float4*)&av[4]  = *(const float4*)(ap0 + k0 + 4);
        *(float4*)&av[8]  = *(const float4*)(ap0 + k0 + 8);
        *(float4*)&av[12] = *(const float4*)(ap0 + k0 + 12);
        *(float4*)&bv[0]  = *(const float4*)(bp0 + k0);
        *(float4*)&bv[4]  = *(const float4*)(bp0 + k0 + 4);
        *(float4*)&bv[8]  = *(const float4*)(bp0 + k0 + 8);
        *(float4*)&bv[12] = *(const float4*)(bp0 + k0 + 12);
        *(float4*)&wv[0]  = *(const float4*)(w2 + k0 + scol);
        *(float4*)&wv[4]  = *(const float4*)(w2 + k0 + scol + 4);
        *(float4*)&wv[8]  = *(const float4*)(w2 + k0 + scol + 8);
        *(float4*)&wv[12] = *(const float4*)(w2 + k0 + scol + 12);
        *(float4*)&wc[0]  = *(const float4*)(w1 + k0 + scol);
        *(float4*)&wc[4]  = *(const float4*)(w1 + k0 + scol + 4);
        *(float4*)&wc[8]  = *(const float4*)(w1 + k0 + scol + 8);
        *(float4*)&wc[12] = *(const float4*)(w1 + k0 + scol + 12);
        *(float4*)&wq[0]  = *(const float4*)(w1 + 512 + k0 + scol);
        *(float4*)&wq[4]  = *(const float4*)(w1 + 512 + k0 + scol + 4);
        *(float4*)&wq[8]  = *(const float4*)(w1 + 512 + k0 + scol + 8);
        *(float4*)&wq[12] = *(const float4*)(w1 + 512 + k0 + scol + 12);
#pragma unroll
        for (int j = 0; j < 16; j++) { pcw += av[j] * wc[j]; pqw += bv[j] * wq[j]; }
        unsigned int ahw[8], alw[8], bhw[8], blw[8];
#pragma unroll
        for (int j = 0; j < 8; j++) {
            float p0 = av[2 * j] * wv[2 * j], p1 = av[2 * j + 1] * wv[2 * j + 1];
            unsigned short h0, s0, h1, s1;
            bfsplit(p0, h0, s0); bfsplit(p1, h1, s1);
            ahw[j] = (unsigned int)h0 | ((unsigned int)h1 << 16);
            alw[j] = (unsigned int)s0 | ((unsigned int)s1 << 16);
            unsigned short g0, t0, g1, t1;
            bfsplit(bv[2 * j], g0, t0); bfsplit(bv[2 * j + 1], g1, t1);
            bhw[j] = (unsigned int)g0 | ((unsigned int)g1 << 16);
            blw[j] = (unsigned int)t0 | ((unsigned int)t1 << 16);
        }
        __syncthreads();
        *(uint4*)&Ah[srow][scol]     = *(uint4*)&ahw[0];
        *(uint4*)&Ah[srow][scol + 8] = *(uint4*)&ahw[4];
        *(uint4*)&Al[srow][scol]     = *(uint4*)&alw[0];
        *(uint4*)&Al[srow][scol + 8] = *(uint4*)&alw[4];
        *(uint4*)&Bh[srow][scol]     = *(uint4*)&bhw[0];
        *(uint4*)&Bh[srow][scol + 8] = *(uint4*)&bhw[4];
        *(uint4*)&Bl[srow][scol]     = *(uint4*)&blw[0];
        *(uint4*)&Bl[srow][scol + 8] = *(uint4*)&blw[4];
        __syncthreads();
        short8 afh[4], afl[4], bfh[4], bfl[4];
#pragma unroll
        for (int i = 0; i < 4; i++) {
            afh[i] = *(const short8*)&Ah[wm + i * 16 + lr][koff];
            afl[i] = *(const short8*)&Al[wm + i * 16 + lr][koff];
            bfh[i] = *(const short8*)&Bh[wn + i * 16 + lr][koff];
            bfl[i] = *(const short8*)&Bl[wn + i * 16 + lr][koff];
        }
#pragma unroll
        for (int i = 0; i < 4; i++)
#pragma unroll
            for (int j = 0; j < 4; j++) {
                acc[i][j] = __builtin_amdgcn_mfma_f32_16x16x32_bf16(afl[i], bfh[j], acc[i][j], 0, 0, 0);
                acc[i][j] = __builtin_amdgcn_mfma_f32_16x16x32_bf16(afh[i], bfl[j], acc[i][j], 0, 0, 0);
                acc[i][j] = __builtin_amdgcn_mfma_f32_16x16x32_bf16(afh[i], bfh[j], acc[i][j], 0, 0, 0);
            }
    }
    // pair-reduce the cw/qw partial dots (lanes tid, tid^1 share srow)
    pcw += __shfl_xor(pcw, 1);
    pqw += __shfl_xor(pqw, 1);
    if ((tid & 1) == 0) { cwl[srow] = pcw; qwl[srow] = pqw; }
    __syncthreads();
    float bsum = bvec[0] + bvec[1] + bvec[2];
    int quad = l >> 4;
#pragma unroll
    for (int i = 0; i < 4; i++) {
#pragma unroll
        for (int j = 0; j < 4; j++) {
            int n = n0 + wn + j * 16 + lr;
            float qwv = qwl[wn + j * 16 + lr] + bsum;
#pragma unroll
            for (int r = 0; r < 4; r++) {
                int m = m0 + wm + i * 16 + quad * 4 + r;
                smat[((size_t)(b * 256 + m)) * 256 + n] =
                    acc[i][j][r] + cwl[wm + i * 16 + quad * 4 + r] + qwv;
            }
        }
    }
}

__global__ void softmax_kernel(float* __restrict__ smat, float* __restrict__ rowmax) {
    int row = blockIdx.x;
    int lane = threadIdx.x;
    float* p = smat + (size_t)row * LSEQ;
    float v[4];
    float mx = -1e30f;
#pragma unroll
    for (int j = 0; j < 4; j++) { v[j] = p[lane + j * 64]; mx = fmaxf(mx, v[j]); }
    for (int off = 32; off; off >>= 1) mx = fmaxf(mx, __shfl_down(mx, off));
    mx = __shfl(mx, 0);
    float sum = 0.f;
#pragma unroll
    for (int j = 0; j < 4; j++) { v[j] = __expf(v[j] - mx); sum += v[j]; }
    for (int off = 32; off; off >>= 1) sum += __shfl_down(sum, off);
    sum = __shfl(sum, 0);
    float inv = 1.f / sum;
#pragma unroll
    for (int j = 0; j < 4; j++) p[lane + j * 64] = v[j] * inv;
    if (lane == 0) rowmax[row] = mx;
}

__global__ void bb_kernel(const float* __restrict__ rowmax, float* __restrict__ bb) {
    int b = blockIdx.x; int t = threadIdx.x;
    __shared__ float red[256];
    float v = rowmax[b * LSEQ + t];
    red[t] = v; __syncthreads();
    for (int s = 128; s; s >>= 1) { if (t < s) red[t] = fmaxf(red[t], red[t + s]); __syncthreads(); }
    float mx = red[0]; __syncthreads();
    float e = __expf(v - mx);
    red[t] = e; __syncthreads();
    for (int s = 128; s; s >>= 1) { if (t < s) red[t] += red[t + s]; __syncthreads(); }
    bb[b * LSEQ + t] = e / red[0];
}

// q2c: grid (64,4) x 128 thr; 4 independent accumulators break the add chain
__global__ void q2c_kernel(const float* __restrict__ bb, const float* __restrict__ c,
                           float* __restrict__ q2c) {
    int b = blockIdx.x;
    int d = blockIdx.y * 128 + threadIdx.x;
    const float* cb = c + (size_t)b * LSEQ * H2 + d;
    const float* bbp = bb + b * LSEQ;
    float a0 = 0.f, a1 = 0.f, a2 = 0.f, a3 = 0.f;
    for (int i = 0; i < LSEQ; i += 4) {
        a0 += bbp[i]     * cb[(size_t)i * H2];
        a1 += bbp[i + 1] * cb[(size_t)(i + 1) * H2];
        a2 += bbp[i + 2] * cb[(size_t)(i + 2) * H2];
        a3 += bbp[i + 3] * cb[(size_t)(i + 3) * H2];
    }
    q2c[b * H2 + d] = (a0 + a1) + (a2 + a3);
}

// c2q via MFMA split-bf16 with FUSED fixup03 epilogue; ATT stored as bf16.
// add-mode = bf16 read-modify-write.
__global__ __launch_bounds__(256)
void c2q_fix_mfma(const float* __restrict__ amat, const float* __restrict__ q,
                  const float* __restrict__ c, const float* __restrict__ q2c,
                  unsigned short* __restrict__ att, int add) {
    __shared__ __align__(16) unsigned short Ah[128][40];
    __shared__ __align__(16) unsigned short Al[128][40];
    __shared__ __align__(16) unsigned short Bh[128][40];
    __shared__ __align__(16) unsigned short Bl[128][40];
    int b = blockIdx.z;
    int m0 = blockIdx.x * 128, n0 = blockIdx.y * 128;
    int tid = threadIdx.x;
    int l = tid & 63, w = tid >> 6;
    int wm = (w & 1) * 64, wn = (w >> 1) * 64;
    int lr = l & 15, koff = (l >> 4) * 8;
    int srow = tid >> 1, scol = (tid & 1) * 16;
    int bn = tid & 127, bkh = tid >> 7;           // B-stage: column n0+bn, k-half bkh
    floatx4 acc[4][4];
#pragma unroll
    for (int i = 0; i < 4; i++)
#pragma unroll
        for (int j = 0; j < 4; j++) acc[i][j] = (floatx4){0.f, 0.f, 0.f, 0.f};
    for (int k0 = 0; k0 < LSEQ; k0 += 32) {
        float av[16];
        const float* ap = amat + (size_t)(b * 256 + m0 + srow) * 256 + k0 + scol;
        *(float4*)&av[0]  = *(const float4*)(ap);
        *(float4*)&av[4]  = *(const float4*)(ap + 4);
        *(float4*)&av[8]  = *(const float4*)(ap + 8);
        *(float4*)&av[12] = *(const float4*)(ap + 12);
        float qv[16];
        const float* qp = q + (size_t)(b * 256 + k0 + bkh * 16) * H2 + n0 + bn;
#pragma unroll
        for (int j = 0; j < 16; j++) qv[j] = qp[(size_t)j * H2];
        unsigned int ahw[8], alw[8], bhw[8], blw[8];
#pragma unroll
        for (int j = 0; j < 8; j++) {
            unsigned short h0, s0, h1, s1;
            bfsplit(av[2 * j], h0, s0); bfsplit(av[2 * j + 1], h1, s1);
            ahw[j] = (unsigned int)h0 | ((unsigned int)h1 << 16);
            alw[j] = (unsigned int)s0 | ((unsigned int)s1 << 16);
            unsigned short g0, t0, g1, t1;
            bfsplit(qv[2 * j], g0, t0); bfsplit(qv[2 * j + 1], g1, t1);
            bhw[j] = (unsigned int)g0 | ((unsigned int)g1 << 16);
            blw[j] = (unsigned int)t0 | ((unsigned int)t1 << 16);
        }
        __syncthreads();
        *(uint4*)&Ah[srow][scol]         = *(uint4*)&ahw[0];
        *(uint4*)&Ah[srow][scol + 8]     = *(uint4*)&ahw[4];
        *(uint4*)&Al[srow][scol]         = *(uint4*)&alw[0];
        *(uint4*)&Al[srow][scol + 8]     = *(uint4*)&alw[4];
        *(uint4*)&Bh[bn][bkh * 16]       = *(uint4*)&bhw[0];
        *(uint4*)&Bh[bn][bkh * 16 + 8]   = *(uint4*)&bhw[4];
        *(uint4*)&Bl[bn][bkh * 16]       = *(uint4*)&blw[0];
        *(uint4*)&Bl[bn][bkh * 16 + 8]   = *(uint4*)&blw[4];
        __syncthreads();
        short8 afh[4], afl[4], bfh[4], bfl[4];
#pragma unroll
        for (int i = 0; i < 4; i++) {
            afh[i] = *(const short8*)&Ah[wm + i * 16 + lr][koff];
            afl[i] = *(const short8*)&Al[wm + i * 16 + lr][koff];
            bfh[i] = *(const short8*)&Bh[wn + i * 16 + lr][koff];
            bfl[i] = *(const short8*)&Bl[wn + i * 16 + lr][koff];
        }
#pragma unroll
        for (int i = 0; i < 4; i++)
#pragma unroll
            for (int j = 0; j < 4; j++) {
                acc[i][j] = __builtin_amdgcn_mfma_f32_16x16x32_bf16(afl[i], bfh[j], acc[i][j], 0, 0, 0);
                acc[i][j] = __builtin_amdgcn_mfma_f32_16x16x32_bf16(afh[i], bfl[j], acc[i][j], 0, 0, 0);
                acc[i][j] = __builtin_amdgcn_mfma_f32_16x16x32_bf16(afh[i], bfh[j], acc[i][j], 0, 0, 0);
            }
    }
    int quad = l >> 4;
#pragma unroll
    for (int i = 0; i < 4; i++) {
#pragma unroll
        for (int j = 0; j < 4; j++) {
            int n = n0 + wn + j * 16 + lr;
            float q2cv = q2c[b * H2 + n];
#pragma unroll
            for (int r = 0; r < 4; r++) {
                int m = m0 + wm + i * 16 + quad * 4 + r;
                size_t row = (size_t)b * 256 + m;
                float a = acc[i][j][r];
                float cv = c[row * H2 + n];
                float v0 = fmaxf(cv, 0.f);
                float v1 = fmaxf(a, 0.f);
                float v2 = fmaxf(cv * a, 0.f);
                float v3 = fmaxf(cv * q2cv, 0.f);
                unsigned short* p0 = att + row * H8 + n;
                if (add) {
                    p0[0]    = f2bf(bf2f(p0[0])    + v0);
                    p0[512]  = f2bf(bf2f(p0[512])  + v1);
                    p0[1024] = f2bf(bf2f(p0[1024]) + v2);
                    p0[1536] = f2bf(bf2f(p0[1536]) + v3);
                } else {
                    p0[0] = f2bf(v0); p0[512] = f2bf(v1);
                    p0[1024] = f2bf(v2); p0[1536] = f2bf(v3);
                }
            }
        }
    }
}

// ---------------- final rank reduce (bf16 s) ----------------
__global__ void reduce1_kernel(const unsigned short* __restrict__ s, const float* __restrict__ rw,
                               float* __restrict__ part) {
    int bo = blockIdx.x;
    int p = blockIdx.y;
    int t = threadIdx.x;
    const unsigned int* s0 = (const unsigned int*)(s + (size_t)(2 * bo) * 524288 + (size_t)p * 65536);
    const unsigned int* s1 = (const unsigned int*)(s + (size_t)(2 * bo) * 524288 + 524288 + (size_t)p * 65536);
    const float* rwp = rw + (size_t)p * 65536;
    float acc = 0.f;
    for (int j = t; j < 32768; j += 256) {
        unsigned int a = s0[j], b = s1[j];
        float2 rv = *(const float2*)(rwp + 2 * j);
        float x0 = fmaxf(__uint_as_float(a << 16), __uint_as_float(b << 16));
        float x1 = fmaxf(__uint_as_float(a & 0xFFFF0000u), __uint_as_float(b & 0xFFFF0000u));
        acc += rv.x * x0 + rv.y * x1;
    }
    __shared__ float red[256];
    red[t] = acc; __syncthreads();
    for (int ss = 128; ss; ss >>= 1) { if (t < ss) red[t] += red[t + ss]; __syncthreads(); }
    if (t == 0) part[bo * 8 + p] = red[0];
}

__global__ void reduce2_kernel(const float* __restrict__ part, const float* __restrict__ rb,
                               float* __restrict__ out) {
    int t = threadIdx.x;
    float a = rb[0];
    for (int p = 0; p < 8; p++) a += part[t * 8 + p];
    out[t] = a;
}

extern "C" void kernel_launch(void* const* d_in, const int* in_sizes, int n_in,
                              void* d_out, int out_size, void* d_ws, size_t ws_size,
                              hipStream_t stream) {
    const int* question = (const int*)d_in[0];
    const int* article  = (const int*)d_in[1];
    const float* emb    = (const float*)d_in[2];
    const float* g1_wih = (const float*)d_in[3];
    const float* g1_whh = (const float*)d_in[4];
    const float* g1_bih = (const float*)d_in[5];
    const float* g1_bhh = (const float*)d_in[6];
    const float* g2_wih = (const float*)d_in[7];
    const float* g2_whh = (const float*)d_in[8];
    const float* g2_bih = (const float*)d_in[9];
    const float* g2_bhh = (const float*)d_in[10];
    const float* b1_w   = (const float*)d_in[11];
    const float* b1_b   = (const float*)d_in[12];
    const float* b2_w   = (const float*)d_in[13];
    const float* b2_b   = (const float*)d_in[14];
    const float* rank_w = (const float*)d_in[15];
    const float* rank_b = (const float*)d_in[16];
    float* ws = (float*)d_ws;
    float* out = (float*)d_out;

    // ---- workspace layout (float offsets; phase-liveness verified) ----
    // weights  [0, 2162688)
    // smallbuf [2162688, 2293760)
    // slot A   [2293760, 6488064):  XEMBB (P1-2) / SMAT (P4,P7)
    // slot A'  [2293760, 14876672): GI2B (P5-6)
    // HBUF     [6488064, 23265280): scan1 out (P3-4); head QH, tail AH
    // AX2      [14876672, 23265280): scan2 out (P6-7)
    // ATTB     [25165824, 41943040): bf16 ATT [16384][2048] (P4 -> end)
    // GI1B     [25165824, 50331648): P2-3 only (dead before ATTB written)
    unsigned short* WPK1  = (unsigned short*)(ws);
    unsigned short* WIH1B = (unsigned short*)(ws + 196608);
    unsigned short* WPK2  = (unsigned short*)(ws + 393216);
    unsigned short* WIH2B = (unsigned short*)(ws + 589824);
    float* RM   = ws + 2195456;
    float* BBv  = ws + 2211840;
    float* Q2C  = ws + 2228224;
    float* PART = ws + 2260992;
    unsigned short* XEMBB = (unsigned short*)(ws + 2293760);
    float*          SMAT  = ws + 2293760;
    unsigned short* GI2B  = (unsigned short*)(ws + 2293760);
    float*          HBUF  = ws + 6488064;
    float*          AX2   = ws + 14876672;
    unsigned short* ATTB  = (unsigned short*)(ws + 25165824);
    unsigned short* GI1B  = (unsigned short*)(ws + 25165824);

    // 1. embed (bf16) + pack all weights to bf16 (single launch)
    embed_kernel<<<32768, 256, 0, stream>>>(question, article, emb, XEMBB);
    pack_weights<<<2112, 256, 0, stream>>>(g1_whh, g1_wih, g2_whh, g2_wih,
                                           WPK1, WIH1B, WPK2, WIH2B);

    // 2. GRU1 input gates, both dirs fused: M=32768 N=1536 K=256
    gemm_2dir<<<dim3(256, 12), 256, 0, stream>>>(
        XEMBB, WIH1B, g1_bih, GI1B, GI1B + (size_t)25165824, 0, 256);
    // 3. GRU1 scan
    gru_scan_rreg<<<256, 512, 0, stream>>>(GI1B, GI1B + (size_t)25165824, WPK1, g1_bhh, HBUF);

    float* QH = HBUF;
    float* AH = HBUF + (size_t)64 * 256 * 512;

    // 4. BiDAF1: c=QH, q=AH -> ATTB bf16 (set); cw/qw fused into smat, fixup fused into c2q
    {
        smat_mfma<<<dim3(2, 2, 64), 256, 0, stream>>>(QH, AH, b1_w, b1_b, SMAT);
        softmax_kernel<<<16384, 64, 0, stream>>>(SMAT, RM);
        bb_kernel<<<64, 256, 0, stream>>>(RM, BBv);
        q2c_kernel<<<dim3(64, 4), 128, 0, stream>>>(BBv, QH, Q2C);
        c2q_fix_mfma<<<dim3(2, 4, 64), 256, 0, stream>>>(SMAT, AH, QH, Q2C, ATTB, 0);
    }

    // 5. GRU2 input gates: reads bf16 ATTB directly (no pack), M=16384 N=1536 K=2048
    gemm_2dir<<<dim3(128, 12), 256, 0, stream>>>(
        ATTB, WIH2B, g2_bih, GI2B, GI2B + (size_t)12582912, 0, 2048);
    // 6. GRU2 scan
    gru_scan_rreg<<<128, 512, 0, stream>>>(GI2B, GI2B + (size_t)12582912, WPK2, g2_bhh, AX2);

    // 7. BiDAF2: c=q=AX2 -> ATTB (bf16 accumulate)
    {
        smat_mfma<<<dim3(2, 2, 64), 256, 0, stream>>>(AX2, AX2, b2_w, b2_b, SMAT);
        softmax_kernel<<<16384, 64, 0, stream>>>(SMAT, RM);
        bb_kernel<<<64, 256, 0, stream>>>(RM, BBv);
        q2c_kernel<<<dim3(64, 4), 128, 0, stream>>>(BBv, AX2, Q2C);
        c2q_fix_mfma<<<dim3(2, 4, 64), 256, 0, stream>>>(SMAT, AX2, AX2, Q2C, ATTB, 1);
    }

    // 8. rank reduce (bf16 s)
    reduce1_kernel<<<dim3(32, 8), 256, 0, stream>>>(ATTB, rank_w, PART);
    reduce2_kernel<<<1, 32, 0, stream>>>(PART, rank_b, out);
}